// Round 11
// baseline (501.294 us; speedup 1.0000x reference)
//
#include <hip/hip_runtime.h>
#include <hip/hip_bf16.h>

// Problem constants (from reference)
#define LSEQ   2048
#define BSZN   2
#define DMODEL 1024
#define NHEAD  16
#define DH     64
#define MPROJ  256
#define PF     512   // 2*MPROJ feature dim
#define CHK    64    // chunk length
#define NCHK   32    // LSEQ/CHK
#define BHN    32    // BSZN*NHEAD
#define NQKV   3088  // NHEAD*(3*DH+1)
#define NQPAD  3200  // NQKV padded to 25*128

typedef __hip_bfloat16 bf16;
typedef short bf16x8 __attribute__((ext_vector_type(8)));
typedef float f32x4 __attribute__((ext_vector_type(4)));

#define MFMA(a, b, c) __builtin_amdgcn_mfma_f32_16x16x32_bf16(a, b, c, 0, 0, 0)

// unpack a u32 holding two bf16 (little-endian: low half = first element)
#define UNP(u, a, b) { a = __uint_as_float((unsigned)(u) << 16); b = __uint_as_float((unsigned)(u) & 0xffff0000u); }

static __device__ __forceinline__ float b2f(bf16 x) {
  unsigned short us = *(unsigned short*)&x;
  return __uint_as_float((unsigned)us << 16);
}
static __device__ __forceinline__ bf16 f2b(float x) { return __float2bfloat16(x); }
static __device__ __forceinline__ unsigned pkbf(float a, float b) {
  bf16 x = __float2bfloat16(a), y = __float2bfloat16(b);
  return ((unsigned)(*(unsigned short*)&y) << 16) | (unsigned)(*(unsigned short*)&x);
}

// async global->LDS, 16B per lane. gsrc is PER-LANE; ldst wave-uniform base.
static __device__ __forceinline__ void gl_lds16(const void* gsrc, void* ldst) {
  __builtin_amdgcn_global_load_lds(
      (const __attribute__((address_space(1))) unsigned int*)gsrc,
      (__attribute__((address_space(3))) unsigned int*)ldst, 16, 0, 0);
}

#define MEMFENCE asm volatile("" ::: "memory")
#define WAITV(n) asm volatile("s_waitcnt vmcnt(" #n ")" ::: "memory")
#define WAITLGKM asm volatile("s_waitcnt lgkmcnt(0)" ::: "memory")
#define BARRIER() __builtin_amdgcn_s_barrier()

// ---------------------------------------------------------------------------
// K0a: h (f32) -> hbf (bf16), pre-swizzled: within each 64-elem group, 16B
// unit u stored at u ^ (row&7).
// ---------------------------------------------------------------------------
__global__ __launch_bounds__(256)
void k_cvth(const float* __restrict__ h, bf16* __restrict__ hbf)
{
  const int gt = blockIdx.x * 256 + threadIdx.x;   // unit id, 4096*128 total
  const int r = gt >> 7, ug = gt & 127;
  const int grp = ug >> 3, u = ug & 7;
  const float4 f0 = *(const float4*)&h[(size_t)r * 1024 + grp * 64 + u * 8];
  const float4 f1 = *(const float4*)&h[(size_t)r * 1024 + grp * 64 + u * 8 + 4];
  uint4 o;
  o.x = pkbf(f0.x, f0.y); o.y = pkbf(f0.z, f0.w);
  o.z = pkbf(f1.x, f1.y); o.w = pkbf(f1.z, f1.w);
  *(uint4*)&hbf[(size_t)r * 1024 + grp * 64 + ((u ^ (r & 7)) << 3)] = o;
}

// ---------------------------------------------------------------------------
// K0b: W [1024][nsrc] f32 -> WT [gridDim.x*64][1024] bf16 transposed,
// pre-swizzled, zero-padded rows beyond nsrc.
// ---------------------------------------------------------------------------
__global__ __launch_bounds__(256)
void k_cvtw(const float* __restrict__ W, bf16* __restrict__ WT, int nsrc)
{
  __shared__ float sT[64][65];
  const int tid = threadIdx.x;
  const int n0 = blockIdx.x * 64, k0 = blockIdx.y * 64;
#pragma unroll
  for (int j = 0; j < 16; j++) {
    const int e = j * 256 + tid;
    const int r = e >> 6, c = e & 63;
    sT[r][c] = (n0 + c < nsrc) ? W[(size_t)(k0 + r) * nsrc + n0 + c] : 0.f;
  }
  __syncthreads();
#pragma unroll
  for (int j = 0; j < 2; j++) {
    const int uid = j * 256 + tid;
    const int rp = uid >> 3, u = uid & 7;
    uint4 o;
    o.x = pkbf(sT[u * 8 + 0][rp], sT[u * 8 + 1][rp]);
    o.y = pkbf(sT[u * 8 + 2][rp], sT[u * 8 + 3][rp]);
    o.z = pkbf(sT[u * 8 + 4][rp], sT[u * 8 + 5][rp]);
    o.w = pkbf(sT[u * 8 + 6][rp], sT[u * 8 + 7][rp]);
    *(uint4*)&WT[(size_t)(n0 + rp) * 1024 + k0 + ((u ^ (rp & 7)) << 3)] = o;
  }
}

// ---------------------------------------------------------------------------
// K0c: pm [64][256] f32 -> pmT hi/lo [256 n][64 d] bf16 (split compensation),
// scaled by 64^-0.25 = 2^-1.5, transposed, row-swizzled (key n&7).
// ---------------------------------------------------------------------------
__global__ __launch_bounds__(256)
void k_cvtpm(const float* __restrict__ pm, bf16* __restrict__ pmThi,
             bf16* __restrict__ pmTlo)
{
  const int n = threadIdx.x;
  float v[64];
#pragma unroll
  for (int d = 0; d < 64; d++) v[d] = pm[d * MPROJ + n] * 0.35355339059327373f;
  const int key = n & 7;
#pragma unroll
  for (int u = 0; u < 8; u++) {
    unsigned hi[4], lo[4];
#pragma unroll
    for (int j = 0; j < 4; j++) {
      const float a = v[u * 8 + j * 2], b = v[u * 8 + j * 2 + 1];
      const bf16 ah = f2b(a), bh_ = f2b(b);
      const float ar = a - b2f(ah), br = b - b2f(bh_);
      hi[j] = ((unsigned)(*(const unsigned short*)&bh_) << 16) | (unsigned)(*(const unsigned short*)&ah);
      const bf16 al = f2b(ar), bl = f2b(br);
      lo[j] = ((unsigned)(*(const unsigned short*)&bl) << 16) | (unsigned)(*(const unsigned short*)&al);
    }
    *(uint4*)&pmThi[(size_t)n * 64 + ((u ^ key) << 3)] = make_uint4(hi[0], hi[1], hi[2], hi[3]);
    *(uint4*)&pmTlo[(size_t)n * 64 + ((u ^ key) << 3)] = make_uint4(lo[0], lo[1], lo[2], lo[3]);
  }
}

// ---------------------------------------------------------------------------
// MFMA GEMM core: C[128m x 128n] tile, BK=64, 4 waves (2x2), double-buffered
// global_load_lds staging, xor-swizzled LDS reads (sources pre-swizzled).
// ---------------------------------------------------------------------------
#define GEMM_STAGE(Abase, Bbase, kt, b) {                                      \
  const size_t kb = (size_t)(kt) * 128;   /* byte offset of k-window */        \
  _Pragma("unroll")                                                            \
  for (int j = 0; j < 4; j++) {                                                \
    const int row = (w * 4 + j) * 8 + (lane >> 3);                             \
    gl_lds16((const char*)(Abase) + (size_t)(m0 + row) * 2048 + kb + (lane & 7) * 16, \
             &sA[b][(w * 4 + j) * 1024]);                                      \
  }                                                                            \
  _Pragma("unroll")                                                            \
  for (int j = 0; j < 4; j++) {                                                \
    const int row = (w * 4 + j) * 8 + (lane >> 3);                             \
    gl_lds16((const char*)(Bbase) + (size_t)(n0 + row) * 2048 + kb + (lane & 7) * 16, \
             &sB[b][(w * 4 + j) * 1024]);                                      \
  } }

#define GEMM_COMPUTE(b) {                                                      \
  _Pragma("unroll")                                                            \
  for (int ks = 0; ks < 2; ks++) {                                             \
    bf16x8 af[4], bfr[4];                                                      \
    _Pragma("unroll")                                                          \
    for (int f = 0; f < 4; f++) {                                              \
      const int row = wm * 64 + f * 16 + l16;                                  \
      af[f] = *(const bf16x8*)&sA[b][row * 128 + (((ks * 4 + lg) ^ xs) << 4)]; \
    }                                                                          \
    _Pragma("unroll")                                                          \
    for (int f = 0; f < 4; f++) {                                              \
      const int row = wn * 64 + f * 16 + l16;                                  \
      bfr[f] = *(const bf16x8*)&sB[b][row * 128 + (((ks * 4 + lg) ^ xs) << 4)]; \
    }                                                                          \
    _Pragma("unroll")                                                          \
    for (int fm = 0; fm < 4; fm++)                                             \
      _Pragma("unroll")                                                        \
      for (int fn = 0; fn < 4; fn++)                                           \
        acc[fm][fn] = MFMA(af[fm], bfr[fn], acc[fm][fn]);                      \
  } }

#define GEMM_PREAMBLE                                                          \
  __shared__ __align__(16) char sA[2][16384];                                  \
  __shared__ __align__(16) char sB[2][16384];                                  \
  const int tid = threadIdx.x, w = tid >> 6, lane = tid & 63;                  \
  const int l16 = lane & 15, lg = lane >> 4;                                   \
  const int wm = w >> 1, wn = w & 1;                                           \
  const int m0 = blockIdx.y * 128, n0 = blockIdx.x * 128;                      \
  const int xs = l16 & 7;                                                      \
  f32x4 acc[4][4];                                                             \
  _Pragma("unroll")                                                            \
  for (int i = 0; i < 4; i++)                                                  \
    _Pragma("unroll")                                                          \
    for (int j = 0; j < 4; j++) acc[i][j] = (f32x4){0.f, 0.f, 0.f, 0.f};

// K1: qkvb = hbf @ WqT^T, epilogue scatters to qh/kh (bf16, PRE-SWIZZLED for
// featm staging), vh (bf16, linear) + sigmoid b.
__global__ __launch_bounds__(256, 2)
void k_gemm_qkvb(const bf16* __restrict__ A, const bf16* __restrict__ B,
                 bf16* __restrict__ qh, bf16* __restrict__ kh,
                 bf16* __restrict__ vh, float* __restrict__ bbuf)
{
  GEMM_PREAMBLE
  GEMM_STAGE(A, B, 0, 0);
  __syncthreads();
  for (int kt = 0; kt < 16; kt++) {
    const int b = kt & 1;
    if (kt < 15) GEMM_STAGE(A, B, kt + 1, b ^ 1);
    GEMM_COMPUTE(b);
    __syncthreads();
  }
#pragma unroll
  for (int fm = 0; fm < 4; fm++)
#pragma unroll
    for (int fn = 0; fn < 4; fn++)
#pragma unroll
      for (int reg = 0; reg < 4; reg++) {
        const int m = m0 + wm * 64 + fm * 16 + lg * 4 + reg;
        const int n = n0 + wn * 64 + fn * 16 + l16;
        if (n >= NQKV) continue;
        const float v = acc[fm][fn][reg];
        const int l = m >> 1, bidx = m & 1;
        const int hd = n / 193;
        const int rem = n - hd * 193;
        const int bhi = bidx * NHEAD + hd;
        const size_t o = ((size_t)bhi * LSEQ + l) * DH;
        if (rem < 64) {
          const int d = rem;
          qh[o + ((((d >> 3) ^ (l & 7)) << 3) | (d & 7))] = f2b(v);
        } else if (rem < 128) {
          const int d = rem - 64;
          kh[o + ((((d >> 3) ^ (l & 7)) << 3) | (d & 7))] = f2b(v);
        } else if (rem < 192) {
          vh[o + rem - 128] = f2b(v);
        } else {
          bbuf[(size_t)bhi * LSEQ + l] = 1.f / (1.f + __expf(-v));
        }
      }
}

// K5a: ao = h + lobf @ WoT^T (f32 out)
__global__ __launch_bounds__(256, 2)
void k_gemm_out(const bf16* __restrict__ A, const bf16* __restrict__ B,
                const float* __restrict__ h, float* __restrict__ ao)
{
  GEMM_PREAMBLE
  GEMM_STAGE(A, B, 0, 0);
  __syncthreads();
  for (int kt = 0; kt < 16; kt++) {
    const int b = kt & 1;
    if (kt < 15) GEMM_STAGE(A, B, kt + 1, b ^ 1);
    GEMM_COMPUTE(b);
    __syncthreads();
  }
#pragma unroll
  for (int fm = 0; fm < 4; fm++)
#pragma unroll
    for (int fn = 0; fn < 4; fn++)
#pragma unroll
      for (int reg = 0; reg < 4; reg++) {
        const int m = m0 + wm * 64 + fm * 16 + lg * 4 + reg;
        const int n = n0 + wn * 64 + fn * 16 + l16;
        const size_t o = (size_t)m * DMODEL + n;
        ao[o] = acc[fm][fn][reg] + h[o];
      }
}

// ---------------------------------------------------------------------------
// K2 v2: FAVOR+ features, orientation-B MFMA (A = pmT, B = x rows).
// ---------------------------------------------------------------------------
__global__ __launch_bounds__(256, 2)
void k_featm(const bf16* __restrict__ qh, const bf16* __restrict__ kh,
             const bf16* __restrict__ pmThi, const bf16* __restrict__ pmTlo,
             bf16* __restrict__ Qp, bf16* __restrict__ Kp)
{
  __shared__ __align__(16) char sPM[2][32768];   // pmT hi, lo [256 n][64 d]
  __shared__ __align__(16) char sX[8192];        // 64 rows x 128 B (q, then k)

  const int tid = threadIdx.x, w = tid >> 6, lane = tid & 63;
  const int l16 = lane & 15, lg = lane >> 4;
  const int xs = l16 & 7;
  const int l0 = blockIdx.x * 64, bhi = blockIdx.y;

#pragma unroll
  for (int j = 0; j < 8; j++)
    gl_lds16((const char*)pmThi + (size_t)(w * 8 + j) * 1024 + lane * 16,
             &sPM[0][(w * 8 + j) * 1024]);
#pragma unroll
  for (int j = 0; j < 8; j++)
    gl_lds16((const char*)pmTlo + (size_t)(w * 8 + j) * 1024 + lane * 16,
             &sPM[1][(w * 8 + j) * 1024]);
  {
    const char* qb = (const char*)(qh + ((size_t)bhi * LSEQ + l0) * DH);
#pragma unroll
    for (int j = 0; j < 2; j++)
      gl_lds16(qb + (size_t)(w * 2 + j) * 1024 + lane * 16, &sX[(w * 2 + j) * 1024]);
  }
  MEMFENCE;
  WAITV(0); BARRIER();

  const int srow = w * 16 + l16;                 // seq row in block (per lane)
  const size_t gsr = (size_t)bhi * LSEQ + l0 + srow;

  for (int wh = 0; wh < 2; wh++) {
    bf16* dst = wh ? Kp : Qp;

    float hn;
    {
      const char* xrow = &sX[srow * 128];
      const uint4 a0 = *(const uint4*)&xrow[lg * 32];
      const uint4 a1 = *(const uint4*)&xrow[lg * 32 + 16];
      float f0, f1, f2, f3, f4, f5, f6, f7, a = 0.f;
      UNP(a0.x, f0, f1); UNP(a0.y, f2, f3); UNP(a0.z, f4, f5); UNP(a0.w, f6, f7);
      a = fmaf(f0, f0, a); a = fmaf(f1, f1, a); a = fmaf(f2, f2, a); a = fmaf(f3, f3, a);
      a = fmaf(f4, f4, a); a = fmaf(f5, f5, a); a = fmaf(f6, f6, a); a = fmaf(f7, f7, a);
      UNP(a1.x, f0, f1); UNP(a1.y, f2, f3); UNP(a1.z, f4, f5); UNP(a1.w, f6, f7);
      a = fmaf(f0, f0, a); a = fmaf(f1, f1, a); a = fmaf(f2, f2, a); a = fmaf(f3, f3, a);
      a = fmaf(f4, f4, a); a = fmaf(f5, f5, a); a = fmaf(f6, f6, a); a = fmaf(f7, f7, a);
      a += __shfl_xor(a, 16); a += __shfl_xor(a, 32);
      hn = a * 0.0625f;
    }

    f32x4 acc[16];
#pragma unroll
    for (int i = 0; i < 16; i++) acc[i] = (f32x4){0.f, 0.f, 0.f, 0.f};
#pragma unroll
    for (int ks = 0; ks < 2; ks++) {
      const bf16x8 bx = *(const bf16x8*)&sX[srow * 128 + (((ks * 4 + lg) ^ xs) << 4)];
#pragma unroll
      for (int mt = 0; mt < 16; mt++) {
        const bf16x8 ah = *(const bf16x8*)&sPM[0][(mt * 16 + l16) * 128 + (((ks * 4 + lg) ^ xs) << 4)];
        acc[mt] = MFMA(ah, bx, acc[mt]);
        const bf16x8 al = *(const bf16x8*)&sPM[1][(mt * 16 + l16) * 128 + (((ks * 4 + lg) ^ xs) << 4)];
        acc[mt] = MFMA(al, bx, acc[mt]);
      }
    }

    if (wh == 0) {
      BARRIER();
      const char* kb = (const char*)(kh + ((size_t)bhi * LSEQ + l0) * DH);
#pragma unroll
      for (int j = 0; j < 2; j++)
        gl_lds16(kb + (size_t)(w * 2 + j) * 1024 + lane * 16, &sX[(w * 2 + j) * 1024]);
      MEMFENCE;
    }

    float ss = 0.f;
#pragma unroll
    for (int mt = 0; mt < 16; mt++)
#pragma unroll
      for (int r = 0; r < 4; r++) {
        const float p = acc[mt][r];
        ss += __expf(p - hn) + __expf(-p - hn);
      }
    ss += __shfl_xor(ss, 16); ss += __shfl_xor(ss, 32);
    const float D = ss + 0.0512f;
    const float cc = 1e-4f / D;
    const float eo = hn + __logf(D);

    const size_t gb = gsr * PF;
    const int half = (lg & 1) * 4;
    const int ub = lg >> 1;
#pragma unroll
    for (int mt = 0; mt < 16; mt++) {
      const float v0 = __expf(acc[mt][0] - eo) + cc;
      const float v1 = __expf(acc[mt][1] - eo) + cc;
      const float v2 = __expf(acc[mt][2] - eo) + cc;
      const float v3 = __expf(acc[mt][3] - eo) + cc;
      const float n0 = __expf(-acc[mt][0] - eo) + cc;
      const float n1 = __expf(-acc[mt][1] - eo) + cc;
      const float n2 = __expf(-acc[mt][2] - eo) + cc;
      const float n3 = __expf(-acc[mt][3] - eo) + cc;
      const int u = mt * 2 + ub;
      *(uint2*)&dst[gb + ((u ^ xs) << 3) + half] = make_uint2(pkbf(v0, v1), pkbf(v2, v3));
      *(uint2*)&dst[gb + (((u + 32) ^ xs) << 3) + half] = make_uint2(pkbf(n0, n1), pkbf(n2, n3));
      __builtin_amdgcn_sched_barrier(0);
    }

    if (wh == 0) { WAITV(32); BARRIER(); }
  }
}

// ---------------------------------------------------------------------------
// K3 (MFMA): per (chunk, bh): S = Kp Kp^T, G = Qp Kp^T via mfma, KpT fused,
// T = (I + tril_strict(diag(b)S))^{-1} diag(b) by 64-lane forward subst.
// Gl is tril-INCLUSIVE, positive (out identity uses W_old).
// ---------------------------------------------------------------------------
__global__ __launch_bounds__(256, 2)
void k_sgsolve(const bf16* __restrict__ Kp, const bf16* __restrict__ Qp,
               const float* __restrict__ bbuf,
               bf16* __restrict__ Gl, bf16* __restrict__ Tm,
               bf16* __restrict__ KpT)
{
  __shared__ __align__(16) char bufK[2][8192];
  __shared__ __align__(16) char bufQ[2][8192];
  __shared__ float sS[CHK][65];
  __shared__ float sT[CHK][65];
  __shared__ float sBeta[CHK];

  const int tid = threadIdx.x, w = tid >> 6, lane = tid & 63;
  const int l16 = lane & 15, lg = lane >> 4;
  const int xs = l16 & 7;
  const int c = blockIdx.x, bhi = blockIdx.y;
  const size_t cb = ((size_t)bhi * LSEQ + (size_t)c * CHK) * PF;
  const size_t rowb = (size_t)bhi * LSEQ + (size_t)c * CHK;
  const size_t ktb = (((size_t)bhi * NCHK + c) * 512) * 64;
  const size_t sb = (((size_t)bhi * NCHK + c) * CHK) * CHK;

  if (tid < CHK) sBeta[tid] = bbuf[rowb + tid];

  f32x4 accS[4], accG[4];
#pragma unroll
  for (int i = 0; i < 4; i++) { accS[i] = (f32x4){0.f,0.f,0.f,0.f}; accG[i] = (f32x4){0.f,0.f,0.f,0.f}; }

#define SG_STAGE(win, b) {                                                     \
  _Pragma("unroll")                                                            \
  for (int j = 0; j < 2; j++) {                                                \
    const int row = w * 16 + j * 8 + (lane >> 3);                              \
    gl_lds16((const char*)(Kp + cb) + (size_t)row * 1024 + (size_t)(win) * 128 + (lane & 7) * 16, \
             &bufK[b][(w * 16 + j * 8) * 128]);                                \
  }                                                                            \
  _Pragma("unroll")                                                            \
  for (int j = 0; j < 2; j++) {                                                \
    const int row = w * 16 + j * 8 + (lane >> 3);                              \
    gl_lds16((const char*)(Qp + cb) + (size_t)row * 1024 + (size_t)(win) * 128 + (lane & 7) * 16, \
             &bufQ[b][(w * 16 + j * 8) * 128]);                                \
  } }

  SG_STAGE(0, 0);
  MEMFENCE;

  for (int win = 0; win < 8; win++) {
    const int b = win & 1;
    if (win < 7) { SG_STAGE(win + 1, b ^ 1); MEMFENCE; }
    if (win == 0)      { WAITV(4); }
    else if (win < 7)  { WAITV(6); }
    else               { WAITV(2); }
    BARRIER();

#pragma unroll
    for (int ks = 0; ks < 2; ks++) {
      const bf16x8 aK = *(const bf16x8*)&bufK[b][(16 * w + l16) * 128 + (((ks * 4 + lg) ^ xs) << 4)];
      const bf16x8 aQ = *(const bf16x8*)&bufQ[b][(16 * w + l16) * 128 + (((ks * 4 + lg) ^ xs) << 4)];
      bf16x8 bK[4];
#pragma unroll
      for (int nt = 0; nt < 4; nt++)
        bK[nt] = *(const bf16x8*)&bufK[b][(nt * 16 + l16) * 128 + (((ks * 4 + lg) ^ xs) << 4)];
#pragma unroll
      for (int nt = 0; nt < 4; nt++) {
        accS[nt] = MFMA(aK, bK[nt], accS[nt]);
        accG[nt] = MFMA(aQ, bK[nt], accG[nt]);
      }
    }

    // KpT emission for this window: KpT[p][l], p = win*64 + pl
#pragma unroll
    for (int jj = 0; jj < 2; jj++) {
      const int idx = jj * 256 + tid;
      const int pl = idx >> 3, l8 = idx & 7;
      unsigned short v[8];
#pragma unroll
      for (int j = 0; j < 8; j++) {
        const int l = l8 * 8 + j;
        v[j] = *(const unsigned short*)&bufK[b][l * 128 + (((pl >> 3) ^ (l & 7)) << 4) + (pl & 7) * 2];
      }
      uint4 o;
      o.x = ((unsigned)v[1] << 16) | v[0];
      o.y = ((unsigned)v[3] << 16) | v[2];
      o.z = ((unsigned)v[5] << 16) | v[4];
      o.w = ((unsigned)v[7] << 16) | v[6];
      const int p = win * 64 + pl;
      *(uint4*)&KpT[ktb + (size_t)p * 64 + ((l8 ^ (p & 7)) << 3)] = o;
    }
    BARRIER();
  }
#undef SG_STAGE

#pragma unroll
  for (int nt = 0; nt < 4; nt++)
#pragma unroll
    for (int reg = 0; reg < 4; reg++) {
      const int ri = 16 * w + lg * 4 + reg;
      const int cj = nt * 16 + l16;
      sS[ri][cj] = accS[nt][reg];
      Gl[sb + ri * 64 + (((cj >> 3) ^ (ri & 7)) << 3) + (cj & 7)] =
          f2b((cj <= ri) ? accG[nt][reg] : 0.f);
    }
  __syncthreads();

  if (tid < CHK) {
    const int j = tid;
    for (int i = 0; i < CHK; i++) {
      float acc = (i == j) ? 1.f : 0.f;
      for (int k = 0; k < i; k++) acc = fmaf(-sS[i][k], sT[k][j], acc);
      sT[i][j] = sBeta[i] * acc;
    }
  }
  __syncthreads();
  for (int t = tid; t < CHK * CHK; t += 256) {
    const int r = t >> 6, ccj = t & 63;
    Tm[sb + r * 64 + (((ccj >> 3) ^ (r & 7)) << 3) + (ccj & 7)] = f2b(sT[r][ccj]);
  }
}

// ---------------------------------------------------------------------------
// K4 v8: 8-wave scan, 3 barriers/chunk. U = T*upre is computed REDUNDANTLY by
// every wave (T frags for all 4 row-tiles in regs) and transposed through a
// per-wave 2KB LDS scratch (ds_write -> lgkmcnt(0) -> ds_read; wave-local, no
// barrier). Removes the sUT cross-wave exchange and its barrier. Barriers:
//   B1: ph1 K-split partials (pbuf[0]); B2: suP visible; B3: ph4 partials
//   (pbuf[1]) + sWT(new) visible. pbuf double-buffered.
// Operands global->VGPR with prefetch-after-last-use (full-chunk cover).
// ---------------------------------------------------------------------------
__global__ __launch_bounds__(512, 2)
void k_scan(const bf16* __restrict__ Kp, const bf16* __restrict__ Qp,
            const bf16* __restrict__ vh, const bf16* __restrict__ Tm,
            const bf16* __restrict__ Gl, const bf16* __restrict__ KpT,
            bf16* __restrict__ lobf)
{
  __shared__ __align__(16) char sWT[16384];     // W shadow [16 d][512 p] bf16
  __shared__ __align__(16) char suP[2048];      // upre^T [16 d][64 l] bf16
  __shared__ __align__(16) char uScr[8][2048];  // per-wave U^T scratch
  __shared__ __align__(16) float pbuf[2][4][16][16];

  const int tid = threadIdx.x;
  const int w = tid >> 6, lane = tid & 63;
  const int l16 = lane & 15, lg = lane >> 4;
  const int wp = w >> 1, h = w & 1;
  const int bhi = blockIdx.x & 31, dq = blockIdx.x >> 5;
  const int bidx = bhi >> 4, hd = bhi & 15;
  const int xs = l16 & 7;
  const int trow = 16 * wp + l16;

  for (int i = tid; i < 4096; i += 512) ((unsigned*)sWT)[i] = 0u;

  f32x4 Wacc[4];
#pragma unroll
  for (int i = 0; i < 4; i++) Wacc[i] = (f32x4){0.f, 0.f, 0.f, 0.f};

  const size_t bh_base = (size_t)bhi * LSEQ * PF;
  const size_t tg0 = ((size_t)bhi * NCHK) * 4096;
  const size_t kt0 = ((size_t)bhi * NCHK) * (512 * 64);

  // per-lane fragment bases (elements)
  const bf16* KpF = Kp + bh_base + (size_t)trow * PF + h * 256;
  const bf16* QpF = Qp + bh_base + (size_t)trow * PF + h * 256;
  const bf16* KTF = KpT + kt0 + (size_t)(64 * w + l16) * 64;

  bf16x8 fKp[8], fQp[8], fKT[8], tf[8];
  bf16x8 gf0 = {}, gf1 = {};
  float v0 = 0.f, v1 = 0.f, v2 = 0.f, v3 = 0.f;

#define LOADKP(c) { const bf16* _b = KpF + (size_t)(c) * CHK * PF;             \
  _Pragma("unroll")                                                            \
  for (int ks = 0; ks < 8; ks++)                                               \
    fKp[ks] = *(const bf16x8*)(_b + (((ks * 4 + lg) ^ xs) << 3)); }
#define LOADQP(c) { const bf16* _b = QpF + (size_t)(c) * CHK * PF;             \
  _Pragma("unroll")                                                            \
  for (int ks = 0; ks < 8; ks++)                                               \
    fQp[ks] = *(const bf16x8*)(_b + (((ks * 4 + lg) ^ xs) << 3)); }
#define LOADKT(c) { const bf16* _b = KTF + (size_t)(c) * (512 * 64);           \
  _Pragma("unroll")                                                            \
  for (int mt = 0; mt < 4; mt++) {                                             \
    fKT[mt * 2]     = *(const bf16x8*)(_b + mt * 16 * 64 + (((    lg) ^ xs) << 3)); \
    fKT[mt * 2 + 1] = *(const bf16x8*)(_b + mt * 16 * 64 + (((4 + lg) ^ xs) << 3)); \
  } }
#define LOADT(c) { const bf16* _t = Tm + tg0 + (size_t)(c) * 4096;             \
  _Pragma("unroll")                                                            \
  for (int t = 0; t < 4; t++) {                                                \
    tf[t * 2]     = *(const bf16x8*)&_t[(t * 16 + l16) * 64 + (((    lg) ^ xs) << 3)]; \
    tf[t * 2 + 1] = *(const bf16x8*)&_t[(t * 16 + l16) * 64 + (((4 + lg) ^ xs) << 3)]; \
  } }
#define LOADVG(c) if (!h) {                                                    \
  const bf16* _g = Gl + tg0 + (size_t)(c) * 4096;                              \
  gf0 = *(const bf16x8*)&_g[trow * 64 + ((lg ^ xs) << 3)];                     \
  gf1 = *(const bf16x8*)&_g[trow * 64 + (((4 + lg) ^ xs) << 3)];               \
  const bf16* _v = vh + ((size_t)bhi * LSEQ + (c) * 64 + wp * 16 + lg * 4) * 64 + dq * 16 + l16; \
  v0 = b2f(_v[0]); v1 = b2f(_v[64]); v2 = b2f(_v[128]); v3 = b2f(_v[192]); }

  LOADKP(0); LOADKT(0); LOADQP(0); LOADT(0); LOADVG(0);
  WAITLGKM; BARRIER();   // sWT zeros visible

  for (int c = 0; c < NCHK; c++) {
    // ---- ph1: partial upre = Kp(half h) * W_old ----
    f32x4 a0v = (f32x4){0.f,0.f,0.f,0.f}, a1v = (f32x4){0.f,0.f,0.f,0.f};
    bf16x8 wb[8];   // W_old B-frags (half h), HELD for ph4
#pragma unroll
    for (int ks = 0; ks < 8; ks += 2) {
      wb[ks] = *(const bf16x8*)&sWT[l16 * 1024 + (((h * 32 + ks * 4 + lg) ^ xs) << 4)];
      a0v = MFMA(fKp[ks], wb[ks], a0v);
      wb[ks + 1] = *(const bf16x8*)&sWT[l16 * 1024 + (((h * 32 + (ks + 1) * 4 + lg) ^ xs) << 4)];
      a1v = MFMA(fKp[ks + 1], wb[ks + 1], a1v);
    }
    if (c < NCHK - 1) LOADKP(c + 1);
    if (h) {
      float4 pv;
      pv.x = a0v[0] + a1v[0]; pv.y = a0v[1] + a1v[1];
      pv.z = a0v[2] + a1v[2]; pv.w = a0v[3] + a1v[3];
      *(float4*)&pbuf[0][wp][l16][lg * 4] = pv;
    }
    WAITLGKM; BARRIER();  // B1: ph1 partials ready

    if (!h) {
      const float4 po = *(const float4*)&pbuf[0][wp][l16][lg * 4];
      const float u0 = v0 - (a0v[0] + a1v[0]) - po.x;
      const float u1 = v1 - (a0v[1] + a1v[1]) - po.y;
      const float u2 = v2 - (a0v[2] + a1v[2]) - po.z;
      const float u3 = v3 - (a0v[3] + a1v[3]) - po.w;
      const int l0r = 16 * wp + lg * 4;
      *(uint2*)&suP[l16 * 128 + (((l0r >> 3) ^ xs) << 4) + (l0r & 7) * 2] =
          make_uint2(pkbf(u0, u1), pkbf(u2, u3));
    }
    WAITLGKM; BARRIER();  // B2: suP ready

    // ---- U = T * upre, computed redundantly by EVERY wave ----
    {
      const bf16x8 sp0 = *(const bf16x8*)&suP[l16 * 128 + ((lg ^ xs) << 4)];
      const bf16x8 sp1 = *(const bf16x8*)&suP[l16 * 128 + (((4 + lg) ^ xs) << 4)];
      f32x4 ua[4];
#pragma unroll
      for (int t = 0; t < 4; t++) {
        ua[t] = (f32x4){0.f, 0.f, 0.f, 0.f};
        ua[t] = MFMA(tf[t * 2], sp0, ua[t]);
        ua[t] = MFMA(tf[t * 2 + 1], sp1, ua[t]);
      }
      if (c < NCHK - 1) LOADT(c + 1);
      // transpose to own scratch (wave-local): [d=l16][l] layout, swizzled
      char* scr = uScr[w];
#pragma unroll
      for (int t = 0; t < 4; t++) {
        const int lout = t * 16 + lg * 4;
        *(uint2*)&scr[l16 * 128 + (((lout >> 3) ^ xs) << 4) + (lout & 7) * 2] =
            make_uint2(pkbf(ua[t][0], ua[t][1]), pkbf(ua[t][2], ua[t][3]));
      }
    }
    WAITLGKM;   // own scratch writes complete (wave-local, no barrier)
    const bf16x8 bu0 = *(const bf16x8*)&uScr[w][l16 * 128 + ((lg ^ xs) << 4)];
    const bf16x8 bu1 = *(const bf16x8*)&uScr[w][l16 * 128 + (((4 + lg) ^ xs) << 4)];

    // ---- ph3: Wacc += KpT(p-strip) * U ----
#pragma unroll
    for (int mt = 0; mt < 4; mt++) {
      Wacc[mt] = MFMA(fKT[mt * 2], bu0, Wacc[mt]);
      Wacc[mt] = MFMA(fKT[mt * 2 + 1], bu1, Wacc[mt]);
    }
    if (c < NCHK - 1) LOADKT(c + 1);
    // sWT <- bf16(W_new); readers are next chunk's ph1 (after B3)
#pragma unroll
    for (int mt = 0; mt < 4; mt++) {
      const int p0m = w * 64 + mt * 16 + lg * 4;
      *(uint2*)&sWT[l16 * 1024 + (((p0m >> 3) ^ xs) << 4) + (p0m & 7) * 2] =
          make_uint2(pkbf(Wacc[mt][0], Wacc[mt][1]), pkbf(Wacc[mt][2], Wacc[mt][3]));
    }

    // ---- ph4: partial out = Qp(half h) * W_old (wb regs) ----
    f32x4 o0 = (f32x4){0.f,0.f,0.f,0.f}, o1 = (f32x4){0.f,0.f,0.f,0.f};
#pragma unroll
    for (int ks = 0; ks < 8; ks += 2) {
      o0 = MFMA(fQp[ks], wb[ks], o0);
      o1 = MFMA(fQp[ks + 1], wb[ks + 1], o1);
    }
    if (c < NCHK - 1) LOADQP(c + 1);
    if (h) {
      float4 pv;
      pv.x = o0[0] + o1[0]; pv.y = o0[1] + o1[1];
      pv.z = o0[2] + o1[2]; pv.w = o0[3] + o1[3];
      *(float4*)&pbuf[1][wp][l16][lg * 4] = pv;
    } else {
      o0 = MFMA(gf0, bu0, o0);   // + Gl * U (tril-inclusive, positive)
      o1 = MFMA(gf1, bu1, o1);
    }
    WAITLGKM; BARRIER();  // B3: out partials + sWT(new) ready

    if (!h) {
      const float4 po = *(const float4*)&pbuf[1][wp][l16][lg * 4];
      const float pr4[4] = {po.x, po.y, po.z, po.w};
      const int colb = hd * 64 + dq * 16 + l16;
#pragma unroll
      for (int reg = 0; reg < 4; reg++) {
        const int l = c * 64 + 16 * wp + lg * 4 + reg;
        const int r = l * BSZN + bidx;
        const int cp = (colb & ~63) | ((((colb >> 3) & 7) ^ (r & 7)) << 3) | (colb & 7);
        lobf[(size_t)r * DMODEL + cp] = f2b(0.125f * (o0[reg] + o1[reg] + pr4[reg]));
      }
    }
    if (c < NCHK - 1) LOADVG(c + 1);
  }
#undef LOADKP
#undef LOADQP
#undef LOADKT
#undef LOADT
#undef LOADVG
}

// ---------------------------------------------------------------------------
// K5b: LayerNorm (unchanged)
// ---------------------------------------------------------------------------
__global__ __launch_bounds__(256)
void k_ln(const float* __restrict__ ao, const float* __restrict__ gamma,
          const float* __restrict__ beta, float* __restrict__ out)
{
  const int row = blockIdx.x;
  const int tid = threadIdx.x;
  __shared__ float r1[4], r2[4];
  const float4 v = *(const float4*)&ao[(size_t)row * DMODEL + tid * 4];
  float s1 = v.x + v.y + v.z + v.w;
  float s2 = v.x * v.x + v.y * v.y + v.z * v.z + v.w * v.w;
  for (int off = 32; off > 0; off >>= 1) {
    s1 += __shfl_down(s1, off);
    s2 += __shfl_down(s2, off);
  }
  if ((tid & 63) == 0) { r1[tid >> 6] = s1; r2[tid >> 6] = s2; }
  __syncthreads();
  const float ts1 = r1[0] + r1[1] + r1[2] + r1[3];
  const float ts2 = r2[0] + r2[1] + r2[2] + r2[3];
  const float mu = ts1 * (1.f / DMODEL);
  const float var = ts2 * (1.f / DMODEL) - mu * mu;
  const float rs = rsqrtf(var + 1e-5f);
  const float4 g = *(const float4*)&gamma[tid * 4];
  const float4 b = *(const float4*)&beta[tid * 4];
  float4 o;
  o.x = (v.x - mu) * rs * g.x + b.x;
  o.y = (v.y - mu) * rs * g.y + b.y;
  o.z = (v.z - mu) * rs * g.z + b.z;
  o.w = (v.w - mu) * rs * g.w + b.w;
  *(float4*)&out[(size_t)row * DMODEL + tid * 4] = o;
}

// ---------------------------------------------------------------------------
extern "C" void kernel_launch(void* const* d_in, const int* in_sizes, int n_in,
                              void* d_out, int out_size, void* d_ws, size_t ws_size,
                              hipStream_t stream)
{
  (void)in_sizes; (void)n_in; (void)out_size; (void)ws_size;
  const float* h   = (const float*)d_in[0];
  const float* Wq  = (const float*)d_in[1];
  const float* Wo  = (const float*)d_in[2];
  const float* gam = (const float*)d_in[3];
  const float* bet = (const float*)d_in[4];
  const float* pm  = (const float*)d_in[5];
  float* out = (float*)d_out;

  char* ws = (char*)d_ws;
  size_t off = 0;
  auto alloc = [&](size_t bytes) -> void* {
    void* p = ws + off;
    off += (bytes + 255) & ~(size_t)255;
    return p;
  };
  // total workspace ~= 229 MB
  bf16*  vh  = (bf16*)alloc((size_t)BHN * LSEQ * DH * 2);            //  8.4 MB
  float* bbf = (float*)alloc((size_t)BHN * LSEQ * 4);                //  0.3 MB
  bf16*  Kp  = (bf16*)alloc((size_t)BHN * LSEQ * PF * 2);            // 67.1 MB
  bf16*  Qp  = (bf16*)alloc((size_t)BHN * LSEQ * PF * 2);            // 67.1 MB
  bf16*  Tm  = (bf16*)alloc((size_t)BHN * NCHK * CHK * CHK * 2);     //  8.4 MB
  bf16*  Gll = (bf16*)alloc((size_t)BHN * NCHK * CHK * CHK * 2);     //  8.4 MB
  char*  R   = (char*)alloc((size_t)BHN * NCHK * 512 * 64 * 2);      // 67.1 MB shared
  bf16*  WoT = (bf16*)alloc((size_t)DMODEL * DMODEL * 2);            //  2.1 MB
  bf16*  pmThi = (bf16*)alloc((size_t)MPROJ * 64 * 2);               // 32 KB
  bf16*  pmTlo = (bf16*)alloc((size_t)MPROJ * 64 * 2);               // 32 KB
  // region R lifetimes:
  //  phase1 (cvt/qkvb/featm): qh(8.4) | kh(8.4) | hbf(8.4) | WqT(6.6)
  //  phase2 (sgsolve/scan):   KpT (67.1)
  //  phase3 (outgemm/ln):     ao (16.8 f32)
  bf16*  qh  = (bf16*)R;
  bf16*  kh  = (bf16*)(R + (size_t)BHN * LSEQ * DH * 2);
  bf16*  hbf = (bf16*)(R + (size_t)2 * BHN * LSEQ * DH * 2);
  bf16*  WqT = (bf16*)(R + (size_t)3 * BHN * LSEQ * DH * 2);
  bf16*  KpT = (bf16*)R;
  float* ao  = (float*)R;
  bf16*  lobf = (bf16*)d_out;   // d_out scratch; fully rewritten by k_ln

  k_cvth     <<<dim3(2048),                       256, 0, stream>>>(h, hbf);
  k_cvtw     <<<dim3(NQPAD / 64, 16),             256, 0, stream>>>(Wq, WqT, NQKV);
  k_cvtw     <<<dim3(DMODEL / 64, 16),            256, 0, stream>>>(Wo, WoT, DMODEL);
  k_cvtpm    <<<dim3(1),                          256, 0, stream>>>(pm, pmThi, pmTlo);
  k_gemm_qkvb<<<dim3(NQPAD / 128, 4096 / 128),    256, 0, stream>>>(hbf, WqT, qh, kh, vh, bbf);
  k_featm    <<<dim3(LSEQ / 64, BHN),             256, 0, stream>>>(qh, kh, pmThi, pmTlo, Qp, Kp);
  k_sgsolve  <<<dim3(NCHK, BHN),                  256, 0, stream>>>(Kp, Qp, bbf, Gll, Tm, KpT);
  k_scan     <<<dim3(128),                        512, 0, stream>>>(Kp, Qp, vh, Tm, Gll, KpT, lobf);
  k_gemm_out <<<dim3(DMODEL / 128, 4096 / 128),   256, 0, stream>>>(lobf, WoT, h, ao);
  k_ln       <<<dim3(4096),                       256, 0, stream>>>(ao, gam, bet, out);
}

// Round 12
// 359.576 us; speedup vs baseline: 1.3941x; 1.3941x over previous
//
#include <hip/hip_runtime.h>
#include <hip/hip_bf16.h>

// Problem constants (from reference)
#define LSEQ   2048
#define BSZN   2
#define DMODEL 1024
#define NHEAD  16
#define DH     64
#define MPROJ  256
#define PF     512   // 2*MPROJ feature dim
#define CHK    64    // chunk length
#define NCHK   32    // LSEQ/CHK
#define BHN    32    // BSZN*NHEAD
#define NQKV   3088  // NHEAD*(3*DH+1)
#define NQPAD  3200  // NQKV padded to 25*128

typedef __hip_bfloat16 bf16;
typedef short bf16x8 __attribute__((ext_vector_type(8)));
typedef float f32x4 __attribute__((ext_vector_type(4)));

#define MFMA(a, b, c) __builtin_amdgcn_mfma_f32_16x16x32_bf16(a, b, c, 0, 0, 0)

// unpack a u32 holding two bf16 (little-endian: low half = first element)
#define UNP(u, a, b) { a = __uint_as_float((unsigned)(u) << 16); b = __uint_as_float((unsigned)(u) & 0xffff0000u); }

static __device__ __forceinline__ float b2f(bf16 x) {
  unsigned short us = *(unsigned short*)&x;
  return __uint_as_float((unsigned)us << 16);
}
static __device__ __forceinline__ bf16 f2b(float x) { return __float2bfloat16(x); }
static __device__ __forceinline__ unsigned pkbf(float a, float b) {
  bf16 x = __float2bfloat16(a), y = __float2bfloat16(b);
  return ((unsigned)(*(unsigned short*)&y) << 16) | (unsigned)(*(unsigned short*)&x);
}

// async global->LDS, 16B per lane. gsrc is PER-LANE; ldst wave-uniform base.
static __device__ __forceinline__ void gl_lds16(const void* gsrc, void* ldst) {
  __builtin_amdgcn_global_load_lds(
      (const __attribute__((address_space(1))) unsigned int*)gsrc,
      (__attribute__((address_space(3))) unsigned int*)ldst, 16, 0, 0);
}

#define MEMFENCE asm volatile("" ::: "memory")
#define WAITV(n) asm volatile("s_waitcnt vmcnt(" #n ")" ::: "memory")
#define WAITLGKM asm volatile("s_waitcnt lgkmcnt(0)" ::: "memory")
#define BARRIER() __builtin_amdgcn_s_barrier()

// ---------------------------------------------------------------------------
// K0a: h (f32) -> hbf (bf16), pre-swizzled: within each 64-elem group, 16B
// unit u stored at u ^ (row&7).
// ---------------------------------------------------------------------------
__global__ __launch_bounds__(256)
void k_cvth(const float* __restrict__ h, bf16* __restrict__ hbf)
{
  const int gt = blockIdx.x * 256 + threadIdx.x;   // unit id, 4096*128 total
  const int r = gt >> 7, ug = gt & 127;
  const int grp = ug >> 3, u = ug & 7;
  const float4 f0 = *(const float4*)&h[(size_t)r * 1024 + grp * 64 + u * 8];
  const float4 f1 = *(const float4*)&h[(size_t)r * 1024 + grp * 64 + u * 8 + 4];
  uint4 o;
  o.x = pkbf(f0.x, f0.y); o.y = pkbf(f0.z, f0.w);
  o.z = pkbf(f1.x, f1.y); o.w = pkbf(f1.z, f1.w);
  *(uint4*)&hbf[(size_t)r * 1024 + grp * 64 + ((u ^ (r & 7)) << 3)] = o;
}

// ---------------------------------------------------------------------------
// K0b: W [1024][nsrc] f32 -> WT [gridDim.x*64][1024] bf16 transposed,
// pre-swizzled, zero-padded rows beyond nsrc.
// ---------------------------------------------------------------------------
__global__ __launch_bounds__(256)
void k_cvtw(const float* __restrict__ W, bf16* __restrict__ WT, int nsrc)
{
  __shared__ float sT[64][65];
  const int tid = threadIdx.x;
  const int n0 = blockIdx.x * 64, k0 = blockIdx.y * 64;
#pragma unroll
  for (int j = 0; j < 16; j++) {
    const int e = j * 256 + tid;
    const int r = e >> 6, c = e & 63;
    sT[r][c] = (n0 + c < nsrc) ? W[(size_t)(k0 + r) * nsrc + n0 + c] : 0.f;
  }
  __syncthreads();
#pragma unroll
  for (int j = 0; j < 2; j++) {
    const int uid = j * 256 + tid;
    const int rp = uid >> 3, u = uid & 7;
    uint4 o;
    o.x = pkbf(sT[u * 8 + 0][rp], sT[u * 8 + 1][rp]);
    o.y = pkbf(sT[u * 8 + 2][rp], sT[u * 8 + 3][rp]);
    o.z = pkbf(sT[u * 8 + 4][rp], sT[u * 8 + 5][rp]);
    o.w = pkbf(sT[u * 8 + 6][rp], sT[u * 8 + 7][rp]);
    *(uint4*)&WT[(size_t)(n0 + rp) * 1024 + k0 + ((u ^ (rp & 7)) << 3)] = o;
  }
}

// ---------------------------------------------------------------------------
// K0c: pm [64][256] f32 -> pmT hi/lo [256 n][64 d] bf16 (split compensation),
// scaled by 64^-0.25 = 2^-1.5, transposed, row-swizzled (key n&7).
// ---------------------------------------------------------------------------
__global__ __launch_bounds__(256)
void k_cvtpm(const float* __restrict__ pm, bf16* __restrict__ pmThi,
             bf16* __restrict__ pmTlo)
{
  const int n = threadIdx.x;
  float v[64];
#pragma unroll
  for (int d = 0; d < 64; d++) v[d] = pm[d * MPROJ + n] * 0.35355339059327373f;
  const int key = n & 7;
#pragma unroll
  for (int u = 0; u < 8; u++) {
    unsigned hi[4], lo[4];
#pragma unroll
    for (int j = 0; j < 4; j++) {
      const float a = v[u * 8 + j * 2], b = v[u * 8 + j * 2 + 1];
      const bf16 ah = f2b(a), bh_ = f2b(b);
      const float ar = a - b2f(ah), br = b - b2f(bh_);
      hi[j] = ((unsigned)(*(const unsigned short*)&bh_) << 16) | (unsigned)(*(const unsigned short*)&ah);
      const bf16 al = f2b(ar), bl = f2b(br);
      lo[j] = ((unsigned)(*(const unsigned short*)&bl) << 16) | (unsigned)(*(const unsigned short*)&al);
    }
    *(uint4*)&pmThi[(size_t)n * 64 + ((u ^ key) << 3)] = make_uint4(hi[0], hi[1], hi[2], hi[3]);
    *(uint4*)&pmTlo[(size_t)n * 64 + ((u ^ key) << 3)] = make_uint4(lo[0], lo[1], lo[2], lo[3]);
  }
}

// ---------------------------------------------------------------------------
// MFMA GEMM core: C[128m x 128n] tile, BK=64, 4 waves (2x2), double-buffered
// global_load_lds staging, xor-swizzled LDS reads (sources pre-swizzled).
// ---------------------------------------------------------------------------
#define GEMM_STAGE(Abase, Bbase, kt, b) {                                      \
  const size_t kb = (size_t)(kt) * 128;   /* byte offset of k-window */        \
  _Pragma("unroll")                                                            \
  for (int j = 0; j < 4; j++) {                                                \
    const int row = (w * 4 + j) * 8 + (lane >> 3);                             \
    gl_lds16((const char*)(Abase) + (size_t)(m0 + row) * 2048 + kb + (lane & 7) * 16, \
             &sA[b][(w * 4 + j) * 1024]);                                      \
  }                                                                            \
  _Pragma("unroll")                                                            \
  for (int j = 0; j < 4; j++) {                                                \
    const int row = (w * 4 + j) * 8 + (lane >> 3);                             \
    gl_lds16((const char*)(Bbase) + (size_t)(n0 + row) * 2048 + kb + (lane & 7) * 16, \
             &sB[b][(w * 4 + j) * 1024]);                                      \
  } }

#define GEMM_COMPUTE(b) {                                                      \
  _Pragma("unroll")                                                            \
  for (int ks = 0; ks < 2; ks++) {                                             \
    bf16x8 af[4], bfr[4];                                                      \
    _Pragma("unroll")                                                          \
    for (int f = 0; f < 4; f++) {                                              \
      const int row = wm * 64 + f * 16 + l16;                                  \
      af[f] = *(const bf16x8*)&sA[b][row * 128 + (((ks * 4 + lg) ^ xs) << 4)]; \
    }                                                                          \
    _Pragma("unroll")                                                          \
    for (int f = 0; f < 4; f++) {                                              \
      const int row = wn * 64 + f * 16 + l16;                                  \
      bfr[f] = *(const bf16x8*)&sB[b][row * 128 + (((ks * 4 + lg) ^ xs) << 4)]; \
    }                                                                          \
    _Pragma("unroll")                                                          \
    for (int fm = 0; fm < 4; fm++)                                             \
      _Pragma("unroll")                                                        \
      for (int fn = 0; fn < 4; fn++)                                           \
        acc[fm][fn] = MFMA(af[fm], bfr[fn], acc[fm][fn]);                      \
  } }

#define GEMM_PREAMBLE                                                          \
  __shared__ __align__(16) char sA[2][16384];                                  \
  __shared__ __align__(16) char sB[2][16384];                                  \
  const int tid = threadIdx.x, w = tid >> 6, lane = tid & 63;                  \
  const int l16 = lane & 15, lg = lane >> 4;                                   \
  const int wm = w >> 1, wn = w & 1;                                           \
  const int m0 = blockIdx.y * 128, n0 = blockIdx.x * 128;                      \
  const int xs = l16 & 7;                                                      \
  f32x4 acc[4][4];                                                             \
  _Pragma("unroll")                                                            \
  for (int i = 0; i < 4; i++)                                                  \
    _Pragma("unroll")                                                          \
    for (int j = 0; j < 4; j++) acc[i][j] = (f32x4){0.f, 0.f, 0.f, 0.f};

// K1: qkvb = hbf @ WqT^T, epilogue scatters to qh/kh (bf16, PRE-SWIZZLED for
// featm staging), vh (bf16, linear) + sigmoid b.
__global__ __launch_bounds__(256, 2)
void k_gemm_qkvb(const bf16* __restrict__ A, const bf16* __restrict__ B,
                 bf16* __restrict__ qh, bf16* __restrict__ kh,
                 bf16* __restrict__ vh, float* __restrict__ bbuf)
{
  GEMM_PREAMBLE
  GEMM_STAGE(A, B, 0, 0);
  __syncthreads();
  for (int kt = 0; kt < 16; kt++) {
    const int b = kt & 1;
    if (kt < 15) GEMM_STAGE(A, B, kt + 1, b ^ 1);
    GEMM_COMPUTE(b);
    __syncthreads();
  }
#pragma unroll
  for (int fm = 0; fm < 4; fm++)
#pragma unroll
    for (int fn = 0; fn < 4; fn++)
#pragma unroll
      for (int reg = 0; reg < 4; reg++) {
        const int m = m0 + wm * 64 + fm * 16 + lg * 4 + reg;
        const int n = n0 + wn * 64 + fn * 16 + l16;
        if (n >= NQKV) continue;
        const float v = acc[fm][fn][reg];
        const int l = m >> 1, bidx = m & 1;
        const int hd = n / 193;
        const int rem = n - hd * 193;
        const int bhi = bidx * NHEAD + hd;
        const size_t o = ((size_t)bhi * LSEQ + l) * DH;
        if (rem < 64) {
          const int d = rem;
          qh[o + ((((d >> 3) ^ (l & 7)) << 3) | (d & 7))] = f2b(v);
        } else if (rem < 128) {
          const int d = rem - 64;
          kh[o + ((((d >> 3) ^ (l & 7)) << 3) | (d & 7))] = f2b(v);
        } else if (rem < 192) {
          vh[o + rem - 128] = f2b(v);
        } else {
          bbuf[(size_t)bhi * LSEQ + l] = 1.f / (1.f + __expf(-v));
        }
      }
}

// K5a: ao = h + lobf @ WoT^T (f32 out)
__global__ __launch_bounds__(256, 2)
void k_gemm_out(const bf16* __restrict__ A, const bf16* __restrict__ B,
                const float* __restrict__ h, float* __restrict__ ao)
{
  GEMM_PREAMBLE
  GEMM_STAGE(A, B, 0, 0);
  __syncthreads();
  for (int kt = 0; kt < 16; kt++) {
    const int b = kt & 1;
    if (kt < 15) GEMM_STAGE(A, B, kt + 1, b ^ 1);
    GEMM_COMPUTE(b);
    __syncthreads();
  }
#pragma unroll
  for (int fm = 0; fm < 4; fm++)
#pragma unroll
    for (int fn = 0; fn < 4; fn++)
#pragma unroll
      for (int reg = 0; reg < 4; reg++) {
        const int m = m0 + wm * 64 + fm * 16 + lg * 4 + reg;
        const int n = n0 + wn * 64 + fn * 16 + l16;
        const size_t o = (size_t)m * DMODEL + n;
        ao[o] = acc[fm][fn][reg] + h[o];
      }
}

// ---------------------------------------------------------------------------
// K2 v2: FAVOR+ features, orientation-B MFMA (A = pmT, B = x rows).
// ---------------------------------------------------------------------------
__global__ __launch_bounds__(256, 2)
void k_featm(const bf16* __restrict__ qh, const bf16* __restrict__ kh,
             const bf16* __restrict__ pmThi, const bf16* __restrict__ pmTlo,
             bf16* __restrict__ Qp, bf16* __restrict__ Kp)
{
  __shared__ __align__(16) char sPM[2][32768];   // pmT hi, lo [256 n][64 d]
  __shared__ __align__(16) char sX[8192];        // 64 rows x 128 B (q, then k)

  const int tid = threadIdx.x, w = tid >> 6, lane = tid & 63;
  const int l16 = lane & 15, lg = lane >> 4;
  const int xs = l16 & 7;
  const int l0 = blockIdx.x * 64, bhi = blockIdx.y;

#pragma unroll
  for (int j = 0; j < 8; j++)
    gl_lds16((const char*)pmThi + (size_t)(w * 8 + j) * 1024 + lane * 16,
             &sPM[0][(w * 8 + j) * 1024]);
#pragma unroll
  for (int j = 0; j < 8; j++)
    gl_lds16((const char*)pmTlo + (size_t)(w * 8 + j) * 1024 + lane * 16,
             &sPM[1][(w * 8 + j) * 1024]);
  {
    const char* qb = (const char*)(qh + ((size_t)bhi * LSEQ + l0) * DH);
#pragma unroll
    for (int j = 0; j < 2; j++)
      gl_lds16(qb + (size_t)(w * 2 + j) * 1024 + lane * 16, &sX[(w * 2 + j) * 1024]);
  }
  MEMFENCE;
  WAITV(0); BARRIER();

  const int srow = w * 16 + l16;                 // seq row in block (per lane)
  const size_t gsr = (size_t)bhi * LSEQ + l0 + srow;

  for (int wh = 0; wh < 2; wh++) {
    bf16* dst = wh ? Kp : Qp;

    float hn;
    {
      const char* xrow = &sX[srow * 128];
      const uint4 a0 = *(const uint4*)&xrow[lg * 32];
      const uint4 a1 = *(const uint4*)&xrow[lg * 32 + 16];
      float f0, f1, f2, f3, f4, f5, f6, f7, a = 0.f;
      UNP(a0.x, f0, f1); UNP(a0.y, f2, f3); UNP(a0.z, f4, f5); UNP(a0.w, f6, f7);
      a = fmaf(f0, f0, a); a = fmaf(f1, f1, a); a = fmaf(f2, f2, a); a = fmaf(f3, f3, a);
      a = fmaf(f4, f4, a); a = fmaf(f5, f5, a); a = fmaf(f6, f6, a); a = fmaf(f7, f7, a);
      UNP(a1.x, f0, f1); UNP(a1.y, f2, f3); UNP(a1.z, f4, f5); UNP(a1.w, f6, f7);
      a = fmaf(f0, f0, a); a = fmaf(f1, f1, a); a = fmaf(f2, f2, a); a = fmaf(f3, f3, a);
      a = fmaf(f4, f4, a); a = fmaf(f5, f5, a); a = fmaf(f6, f6, a); a = fmaf(f7, f7, a);
      a += __shfl_xor(a, 16); a += __shfl_xor(a, 32);
      hn = a * 0.0625f;
    }

    f32x4 acc[16];
#pragma unroll
    for (int i = 0; i < 16; i++) acc[i] = (f32x4){0.f, 0.f, 0.f, 0.f};
#pragma unroll
    for (int ks = 0; ks < 2; ks++) {
      const bf16x8 bx = *(const bf16x8*)&sX[srow * 128 + (((ks * 4 + lg) ^ xs) << 4)];
#pragma unroll
      for (int mt = 0; mt < 16; mt++) {
        const bf16x8 ah = *(const bf16x8*)&sPM[0][(mt * 16 + l16) * 128 + (((ks * 4 + lg) ^ xs) << 4)];
        acc[mt] = MFMA(ah, bx, acc[mt]);
        const bf16x8 al = *(const bf16x8*)&sPM[1][(mt * 16 + l16) * 128 + (((ks * 4 + lg) ^ xs) << 4)];
        acc[mt] = MFMA(al, bx, acc[mt]);
      }
    }

    if (wh == 0) {
      BARRIER();
      const char* kb = (const char*)(kh + ((size_t)bhi * LSEQ + l0) * DH);
#pragma unroll
      for (int j = 0; j < 2; j++)
        gl_lds16(kb + (size_t)(w * 2 + j) * 1024 + lane * 16, &sX[(w * 2 + j) * 1024]);
      MEMFENCE;
    }

    float ss = 0.f;
#pragma unroll
    for (int mt = 0; mt < 16; mt++)
#pragma unroll
      for (int r = 0; r < 4; r++) {
        const float p = acc[mt][r];
        ss += __expf(p - hn) + __expf(-p - hn);
      }
    ss += __shfl_xor(ss, 16); ss += __shfl_xor(ss, 32);
    const float D = ss + 0.0512f;
    const float cc = 1e-4f / D;
    const float eo = hn + __logf(D);

    const size_t gb = gsr * PF;
    const int half = (lg & 1) * 4;
    const int ub = lg >> 1;
#pragma unroll
    for (int mt = 0; mt < 16; mt++) {
      const float v0 = __expf(acc[mt][0] - eo) + cc;
      const float v1 = __expf(acc[mt][1] - eo) + cc;
      const float v2 = __expf(acc[mt][2] - eo) + cc;
      const float v3 = __expf(acc[mt][3] - eo) + cc;
      const float n0 = __expf(-acc[mt][0] - eo) + cc;
      const float n1 = __expf(-acc[mt][1] - eo) + cc;
      const float n2 = __expf(-acc[mt][2] - eo) + cc;
      const float n3 = __expf(-acc[mt][3] - eo) + cc;
      const int u = mt * 2 + ub;
      *(uint2*)&dst[gb + ((u ^ xs) << 3) + half] = make_uint2(pkbf(v0, v1), pkbf(v2, v3));
      *(uint2*)&dst[gb + (((u + 32) ^ xs) << 3) + half] = make_uint2(pkbf(n0, n1), pkbf(n2, n3));
      __builtin_amdgcn_sched_barrier(0);
    }

    if (wh == 0) { WAITV(32); BARRIER(); }
  }
}

// ---------------------------------------------------------------------------
// K3 (MFMA): per (chunk, bh): S = Kp Kp^T, G = Qp Kp^T via mfma, KpT fused,
// T = (I + tril_strict(diag(b)S))^{-1} diag(b) by 64-lane forward subst.
// Gl is tril-INCLUSIVE, positive (out identity uses W_old).
// ---------------------------------------------------------------------------
__global__ __launch_bounds__(256, 2)
void k_sgsolve(const bf16* __restrict__ Kp, const bf16* __restrict__ Qp,
               const float* __restrict__ bbuf,
               bf16* __restrict__ Gl, bf16* __restrict__ Tm,
               bf16* __restrict__ KpT)
{
  __shared__ __align__(16) char bufK[2][8192];
  __shared__ __align__(16) char bufQ[2][8192];
  __shared__ float sS[CHK][65];
  __shared__ float sT[CHK][65];
  __shared__ float sBeta[CHK];

  const int tid = threadIdx.x, w = tid >> 6, lane = tid & 63;
  const int l16 = lane & 15, lg = lane >> 4;
  const int xs = l16 & 7;
  const int c = blockIdx.x, bhi = blockIdx.y;
  const size_t cb = ((size_t)bhi * LSEQ + (size_t)c * CHK) * PF;
  const size_t rowb = (size_t)bhi * LSEQ + (size_t)c * CHK;
  const size_t ktb = (((size_t)bhi * NCHK + c) * 512) * 64;
  const size_t sb = (((size_t)bhi * NCHK + c) * CHK) * CHK;

  if (tid < CHK) sBeta[tid] = bbuf[rowb + tid];

  f32x4 accS[4], accG[4];
#pragma unroll
  for (int i = 0; i < 4; i++) { accS[i] = (f32x4){0.f,0.f,0.f,0.f}; accG[i] = (f32x4){0.f,0.f,0.f,0.f}; }

#define SG_STAGE(win, b) {                                                     \
  _Pragma("unroll")                                                            \
  for (int j = 0; j < 2; j++) {                                                \
    const int row = w * 16 + j * 8 + (lane >> 3);                              \
    gl_lds16((const char*)(Kp + cb) + (size_t)row * 1024 + (size_t)(win) * 128 + (lane & 7) * 16, \
             &bufK[b][(w * 16 + j * 8) * 128]);                                \
  }                                                                            \
  _Pragma("unroll")                                                            \
  for (int j = 0; j < 2; j++) {                                                \
    const int row = w * 16 + j * 8 + (lane >> 3);                              \
    gl_lds16((const char*)(Qp + cb) + (size_t)row * 1024 + (size_t)(win) * 128 + (lane & 7) * 16, \
             &bufQ[b][(w * 16 + j * 8) * 128]);                                \
  } }

  SG_STAGE(0, 0);
  MEMFENCE;

  for (int win = 0; win < 8; win++) {
    const int b = win & 1;
    if (win < 7) { SG_STAGE(win + 1, b ^ 1); MEMFENCE; }
    if (win == 0)      { WAITV(4); }
    else if (win < 7)  { WAITV(6); }
    else               { WAITV(2); }
    BARRIER();

#pragma unroll
    for (int ks = 0; ks < 2; ks++) {
      const bf16x8 aK = *(const bf16x8*)&bufK[b][(16 * w + l16) * 128 + (((ks * 4 + lg) ^ xs) << 4)];
      const bf16x8 aQ = *(const bf16x8*)&bufQ[b][(16 * w + l16) * 128 + (((ks * 4 + lg) ^ xs) << 4)];
      bf16x8 bK[4];
#pragma unroll
      for (int nt = 0; nt < 4; nt++)
        bK[nt] = *(const bf16x8*)&bufK[b][(nt * 16 + l16) * 128 + (((ks * 4 + lg) ^ xs) << 4)];
#pragma unroll
      for (int nt = 0; nt < 4; nt++) {
        accS[nt] = MFMA(aK, bK[nt], accS[nt]);
        accG[nt] = MFMA(aQ, bK[nt], accG[nt]);
      }
    }

    // KpT emission for this window: KpT[p][l], p = win*64 + pl
#pragma unroll
    for (int jj = 0; jj < 2; jj++) {
      const int idx = jj * 256 + tid;
      const int pl = idx >> 3, l8 = idx & 7;
      unsigned short v[8];
#pragma unroll
      for (int j = 0; j < 8; j++) {
        const int l = l8 * 8 + j;
        v[j] = *(const unsigned short*)&bufK[b][l * 128 + (((pl >> 3) ^ (l & 7)) << 4) + (pl & 7) * 2];
      }
      uint4 o;
      o.x = ((unsigned)v[1] << 16) | v[0];
      o.y = ((unsigned)v[3] << 16) | v[2];
      o.z = ((unsigned)v[5] << 16) | v[4];
      o.w = ((unsigned)v[7] << 16) | v[6];
      const int p = win * 64 + pl;
      *(uint4*)&KpT[ktb + (size_t)p * 64 + ((l8 ^ (p & 7)) << 3)] = o;
    }
    BARRIER();
  }
#undef SG_STAGE

#pragma unroll
  for (int nt = 0; nt < 4; nt++)
#pragma unroll
    for (int reg = 0; reg < 4; reg++) {
      const int ri = 16 * w + lg * 4 + reg;
      const int cj = nt * 16 + l16;
      sS[ri][cj] = accS[nt][reg];
      Gl[sb + ri * 64 + (((cj >> 3) ^ (ri & 7)) << 3) + (cj & 7)] =
          f2b((cj <= ri) ? accG[nt][reg] : 0.f);
    }
  __syncthreads();

  if (tid < CHK) {
    const int j = tid;
    for (int i = 0; i < CHK; i++) {
      float acc = (i == j) ? 1.f : 0.f;
      for (int k = 0; k < i; k++) acc = fmaf(-sS[i][k], sT[k][j], acc);
      sT[i][j] = sBeta[i] * acc;
    }
  }
  __syncthreads();
  for (int t = tid; t < CHK * CHK; t += 256) {
    const int r = t >> 6, ccj = t & 63;
    Tm[sb + r * 64 + (((ccj >> 3) ^ (r & 7)) << 3) + (ccj & 7)] = f2b(sT[r][ccj]);
  }
}

// ---------------------------------------------------------------------------
// K4 v9: round-9 v5 structure (8 waves, LDS-staged, best measured) with the
// barrier count cut 5 -> 3:
//  - merged suP exchange: U = T*(V - p0) + T*(-p1); h=0 writes suP[0]=V-p0,
//    h=1 writes suP[1]=-p1 concurrently (one barrier); ph2 does 4 MFMAs.
//  - B0 dropped: all cross-chunk LDS hazards re-audited; B4 + barrier-arrival
//    ordering cover them (pbuf ph4-read completes before h=1 can pass B1(c+1)).
//  - Kp-ready wait corrected to vmcnt(8) for h=0 (drains all 8 Kp gl_lds).
// ---------------------------------------------------------------------------
__global__ __launch_bounds__(512, 2)
void k_scan(const bf16* __restrict__ Kp, const bf16* __restrict__ Qp,
            const bf16* __restrict__ vh, const bf16* __restrict__ Tm,
            const bf16* __restrict__ Gl, const bf16* __restrict__ KpT,
            bf16* __restrict__ lobf)
{
  __shared__ __align__(16) char bufA[65536];
  __shared__ __align__(16) char bufB[65536];
  __shared__ __align__(16) char sWT[16384];     // W shadow [16 d][512 p] bf16
  __shared__ __align__(16) char suP[2][2048];   // upre halves [16 d][64 l]
  __shared__ __align__(16) char sUT[2048];      // U^T [16 d][64 l]
  __shared__ __align__(16) float pbuf[4][16][16];

  const int tid = threadIdx.x;
  const int w = tid >> 6, lane = tid & 63;
  const int l16 = lane & 15, lg = lane >> 4;
  const int wp = w >> 1, h = w & 1;
  const int bhi = blockIdx.x & 31, dq = blockIdx.x >> 5;
  const int bidx = bhi >> 4, hd = bhi & 15;
  const int xs = l16 & 7;
  const int trow = 16 * wp + l16;

  char* RA = bufA + w * 8192;   // rows 16wp..+16, p-half h (row stride 512 B)
  char* RB = bufB + w * 8192;   // KpT rows 64w..+64 (row stride 128 B)

  for (int i = tid; i < 4096; i += 512) ((unsigned*)sWT)[i] = 0u;

  f32x4 Wacc[4];
#pragma unroll
  for (int i = 0; i < 4; i++) Wacc[i] = (f32x4){0.f, 0.f, 0.f, 0.f};

  const size_t bh_base = (size_t)bhi * LSEQ * PF;
  const size_t tg0 = ((size_t)bhi * NCHK) * 4096;
  const size_t kt0 = ((size_t)bhi * NCHK) * (512 * 64);

  // prologue: KpT(0) -> RB, Kp(0) -> RA, full drain
  {
    const char* gt = (const char*)(KpT + kt0);
#pragma unroll
    for (int j = 0; j < 8; j++)
      gl_lds16(gt + (size_t)w * 8192 + j * 1024 + lane * 16, RB + j * 1024);
    const char* g = (const char*)(Kp + bh_base);
#pragma unroll
    for (int j = 0; j < 8; j++)
      gl_lds16(g + (size_t)(16 * wp + 2 * j + (lane >> 5)) * 1024 + h * 512 + (lane & 31) * 16,
               RA + j * 1024);
  }
  MEMFENCE;
  WAITV(0); WAITLGKM; BARRIER();

  for (int c = 0; c < NCHK; c++) {
    const size_t cb = bh_base + (size_t)c * CHK * PF;
    const bf16* TmC  = Tm + tg0 + (size_t)c * 4096;
    const bf16* GlC  = Gl + tg0 + (size_t)c * 4096;
    const char* QpC  = (const char*)(Qp + cb);
    const char* KpN  = (const char*)(Kp + cb + CHK * PF);
    const char* KpTN = (const char*)(KpT + kt0 + (size_t)(c + 1) * (512 * 64));

    // top-of-chunk register loads (h=0 only): V4, T2, Gl2
    float v0 = 0.f, v1 = 0.f, v2 = 0.f, v3 = 0.f;
    bf16x8 tf0 = {}, tf1 = {}, gf0 = {}, gf1 = {};
    if (!h) {
      const bf16* vp = vh + ((size_t)bhi * LSEQ + c * 64 + wp * 16 + lg * 4) * 64 + dq * 16 + l16;
      v0 = b2f(vp[0]);   v1 = b2f(vp[64]);
      v2 = b2f(vp[128]); v3 = b2f(vp[192]);
      tf0 = *(const bf16x8*)&TmC[trow * 64 + ((lg ^ xs) << 3)];
      tf1 = *(const bf16x8*)&TmC[trow * 64 + (((4 + lg) ^ xs) << 3)];
      gf0 = *(const bf16x8*)&GlC[trow * 64 + ((lg ^ xs) << 3)];
      gf1 = *(const bf16x8*)&GlC[trow * 64 + (((4 + lg) ^ xs) << 3)];
    }
    MEMFENCE;
    if (!h) { WAITV(8); } else { WAITV(0); }   // Kp(c) in RA ready

    // ---- ph1: partial upre = Kp(half h) * W_old ----
    f32x4 a0v = (f32x4){0.f,0.f,0.f,0.f}, a1v = (f32x4){0.f,0.f,0.f,0.f};
    bf16x8 wb[8];   // W_old B-frags (half h), HELD for ph4
#pragma unroll
    for (int ks = 0; ks < 8; ks += 2) {
      const bf16x8 aa0 = *(const bf16x8*)&RA[l16 * 512 + (((ks * 4 + lg) ^ xs) << 4)];
      wb[ks] = *(const bf16x8*)&sWT[l16 * 1024 + (((h * 32 + ks * 4 + lg) ^ xs) << 4)];
      a0v = MFMA(aa0, wb[ks], a0v);
      const bf16x8 aa1 = *(const bf16x8*)&RA[l16 * 512 + ((((ks + 1) * 4 + lg) ^ xs) << 4)];
      wb[ks + 1] = *(const bf16x8*)&sWT[l16 * 1024 + (((h * 32 + (ks + 1) * 4 + lg) ^ xs) << 4)];
      a1v = MFMA(aa1, wb[ks + 1], a1v);
    }
    // merged exchange: both halves write their suP buffer concurrently
    {
      const int l0r = 16 * wp + lg * 4;
      const int off = l16 * 128 + (((l0r >> 3) ^ xs) << 4) + (l0r & 7) * 2;
      if (h) {
        *(uint2*)&suP[1][off] =
            make_uint2(pkbf(-(a0v[0] + a1v[0]), -(a0v[1] + a1v[1])),
                       pkbf(-(a0v[2] + a1v[2]), -(a0v[3] + a1v[3])));
      } else {
        WAITV(0);   // V/T/G register loads done
        *(uint2*)&suP[0][off] =
            make_uint2(pkbf(v0 - (a0v[0] + a1v[0]), v1 - (a0v[1] + a1v[1])),
                       pkbf(v2 - (a0v[2] + a1v[2]), v3 - (a0v[3] + a1v[3])));
      }
    }
    WAITLGKM; BARRIER();  // B1: both suP halves ready; RA reads done

    // stage Qp(c) -> RA (own region)
#pragma unroll
    for (int j = 0; j < 8; j++)
      gl_lds16(QpC + (size_t)(16 * wp + 2 * j + (lane >> 5)) * 1024 + h * 512 + (lane & 31) * 16,
               RA + j * 1024);
    MEMFENCE;

    // ---- ph2: U = T*suP0 + T*suP1 (h=0 waves) ----
    if (!h) {
      f32x4 ua = (f32x4){0.f,0.f,0.f,0.f};
      ua = MFMA(tf0, *(const bf16x8*)&suP[0][l16 * 128 + ((lg ^ xs) << 4)], ua);
      ua = MFMA(tf1, *(const bf16x8*)&suP[0][l16 * 128 + (((4 + lg) ^ xs) << 4)], ua);
      ua = MFMA(tf0, *(const bf16x8*)&suP[1][l16 * 128 + ((lg ^ xs) << 4)], ua);
      ua = MFMA(tf1, *(const bf16x8*)&suP[1][l16 * 128 + (((4 + lg) ^ xs) << 4)], ua);
      const int l0r = 16 * wp + lg * 4;
      *(uint2*)&sUT[l16 * 128 + (((l0r >> 3) ^ xs) << 4) + (l0r & 7) * 2] =
          make_uint2(pkbf(ua[0], ua[1]), pkbf(ua[2], ua[3]));
    }
    WAITLGKM; BARRIER();  // B2: sUT ready

    // ---- ph3: Wacc += KpT(p-strip) * U ----
    const bf16x8 bu0 = *(const bf16x8*)&sUT[l16 * 128 + ((lg ^ xs) << 4)];
    const bf16x8 bu1 = *(const bf16x8*)&sUT[l16 * 128 + (((4 + lg) ^ xs) << 4)];
#pragma unroll
    for (int mt = 0; mt < 4; mt++) {
      const int pr = mt * 16 + l16;
      const bf16x8 ka0 = *(const bf16x8*)&RB[pr * 128 + ((lg ^ xs) << 4)];
      Wacc[mt] = MFMA(ka0, bu0, Wacc[mt]);
      const bf16x8 ka1 = *(const bf16x8*)&RB[pr * 128 + (((4 + lg) ^ xs) << 4)];
      Wacc[mt] = MFMA(ka1, bu1, Wacc[mt]);
    }
    WAITLGKM;   // RB reads drained before overwrite
    if (c < NCHK - 1) {
#pragma unroll
      for (int j = 0; j < 8; j++)
        gl_lds16(KpTN + (size_t)w * 8192 + j * 1024 + lane * 16, RB + j * 1024);
      MEMFENCE;
    }
    // sWT <- bf16(W_new); readers are next chunk's ph1 (after B4)
#pragma unroll
    for (int mt = 0; mt < 4; mt++) {
      const int p0m = w * 64 + mt * 16 + lg * 4;
      *(uint2*)&sWT[l16 * 1024 + (((p0m >> 3) ^ xs) << 4) + (p0m & 7) * 2] =
          make_uint2(pkbf(Wacc[mt][0], Wacc[mt][1]), pkbf(Wacc[mt][2], Wacc[mt][3]));
    }

    // ---- ph4: partial out = Qp(half h) * W_old (wb regs) ----
    if (c < NCHK - 1) { WAITV(8); } else { WAITV(0); }   // Qp ready
    f32x4 o0 = (f32x4){0.f,0.f,0.f,0.f}, o1 = (f32x4){0.f,0.f,0.f,0.f};
#pragma unroll
    for (int ks = 0; ks < 8; ks += 2) {
      const bf16x8 qa0 = *(const bf16x8*)&RA[l16 * 512 + (((ks * 4 + lg) ^ xs) << 4)];
      o0 = MFMA(qa0, wb[ks], o0);
      const bf16x8 qa1 = *(const bf16x8*)&RA[l16 * 512 + ((((ks + 1) * 4 + lg) ^ xs) << 4)];
      o1 = MFMA(qa1, wb[ks + 1], o1);
    }
    WAITLGKM;   // RA reads drained before overwrite
    if (c < NCHK - 1) {
#pragma unroll
      for (int j = 0; j < 8; j++)
        gl_lds16(KpN + (size_t)(16 * wp + 2 * j + (lane >> 5)) * 1024 + h * 512 + (lane & 31) * 16,
                 RA + j * 1024);
      MEMFENCE;
    }
    if (h) {
      float4 pv;
      pv.x = o0[0] + o1[0]; pv.y = o0[1] + o1[1];
      pv.z = o0[2] + o1[2]; pv.w = o0[3] + o1[3];
      *(float4*)&pbuf[wp][l16][lg * 4] = pv;
    } else {
      o0 = MFMA(gf0, bu0, o0);   // + Gl * U (tril-inclusive, positive)
      o1 = MFMA(gf1, bu1, o1);
    }
    WAITLGKM; BARRIER();  // B4: out partials + sWT(new) ready

    if (!h) {
      const float4 po = *(const float4*)&pbuf[wp][l16][lg * 4];
      const float pr4[4] = {po.x, po.y, po.z, po.w};
      const int colb = hd * 64 + dq * 16 + l16;
#pragma unroll
      for (int reg = 0; reg < 4; reg++) {
        const int l = c * 64 + 16 * wp + lg * 4 + reg;
        const int r = l * BSZN + bidx;
        const int cp = (colb & ~63) | ((((colb >> 3) & 7) ^ (r & 7)) << 3) | (colb & 7);
        lobf[(size_t)r * DMODEL + cp] = f2b(0.125f * (o0[reg] + o1[reg] + pr4[reg]));
      }
    }
  }
}

// ---------------------------------------------------------------------------
// K5b: LayerNorm (unchanged)
// ---------------------------------------------------------------------------
__global__ __launch_bounds__(256)
void k_ln(const float* __restrict__ ao, const float* __restrict__ gamma,
          const float* __restrict__ beta, float* __restrict__ out)
{
  const int row = blockIdx.x;
  const int tid = threadIdx.x;
  __shared__ float r1[4], r2[4];
  const float4 v = *(const float4*)&ao[(size_t)row * DMODEL + tid * 4];
  float s1 = v.x + v.y + v.z + v.w;
  float s2 = v.x * v.x + v.y * v.y + v.z * v.z + v.w * v.w;
  for (int off = 32; off > 0; off >>= 1) {
    s1 += __shfl_down(s1, off);
    s2 += __shfl_down(s2, off);
  }
  if ((tid & 63) == 0) { r1[tid >> 6] = s1; r2[tid >> 6] = s2; }
  __syncthreads();
  const float ts1 = r1[0] + r1[1] + r1[2] + r1[3];
  const float ts2 = r2[0] + r2[1] + r2[2] + r2[3];
  const float mu = ts1 * (1.f / DMODEL);
  const float var = ts2 * (1.f / DMODEL) - mu * mu;
  const float rs = rsqrtf(var + 1e-5f);
  const float4 g = *(const float4*)&gamma[tid * 4];
  const float4 b = *(const float4*)&beta[tid * 4];
  float4 o;
  o.x = (v.x - mu) * rs * g.x + b.x;
  o.y = (v.y - mu) * rs * g.y + b.y;
  o.z = (v.z - mu) * rs * g.z + b.z;
  o.w = (v.w - mu) * rs * g.w + b.w;
  *(float4*)&out[(size_t)row * DMODEL + tid * 4] = o;
}

// ---------------------------------------------------------------------------
extern "C" void kernel_launch(void* const* d_in, const int* in_sizes, int n_in,
                              void* d_out, int out_size, void* d_ws, size_t ws_size,
                              hipStream_t stream)
{
  (void)in_sizes; (void)n_in; (void)out_size; (void)ws_size;
  const float* h   = (const float*)d_in[0];
  const float* Wq  = (const float*)d_in[1];
  const float* Wo  = (const float*)d_in[2];
  const float* gam = (const float*)d_in[3];
  const float* bet = (const float*)d_in[4];
  const float* pm  = (const float*)d_in[5];
  float* out = (float*)d_out;

  char* ws = (char*)d_ws;
  size_t off = 0;
  auto alloc = [&](size_t bytes) -> void* {
    void* p = ws + off;
    off += (bytes + 255) & ~(size_t)255;
    return p;
  };
  // total workspace ~= 229 MB
  bf16*  vh  = (bf16*)alloc((size_t)BHN * LSEQ * DH * 2);            //  8.4 MB
  float* bbf = (float*)alloc((size_t)BHN * LSEQ * 4);                //  0.3 MB
  bf16*  Kp  = (bf16*)alloc((size_t)BHN * LSEQ * PF * 2);            // 67.1 MB
  bf16*  Qp  = (bf16*)alloc((size_t)BHN * LSEQ * PF * 2);            // 67.1 MB
  bf16*  Tm  = (bf16*)alloc((size_t)BHN * NCHK * CHK * CHK * 2);     //  8.4 MB
  bf16*  Gll = (bf16*)alloc((size_t)BHN * NCHK * CHK * CHK * 2);     //  8.4 MB
  char*  R   = (char*)alloc((size_t)BHN * NCHK * 512 * 64 * 2);      // 67.1 MB shared
  bf16*  WoT = (bf16*)alloc((size_t)DMODEL * DMODEL * 2);            //  2.1 MB
  bf16*  pmThi = (bf16*)alloc((size_t)MPROJ * 64 * 2);               // 32 KB
  bf16*  pmTlo = (bf16*)alloc((size_t)MPROJ * 64 * 2);               // 32 KB
  // region R lifetimes:
  //  phase1 (cvt/qkvb/featm): qh(8.4) | kh(8.4) | hbf(8.4) | WqT(6.6)
  //  phase2 (sgsolve/scan):   KpT (67.1)
  //  phase3 (outgemm/ln):     ao (16.8 f32)
  bf16*  qh  = (bf16*)R;
  bf16*  kh  = (bf16*)(R + (size_t)BHN * LSEQ * DH * 2);
  bf16*  hbf = (bf16*)(R + (size_t)2 * BHN * LSEQ * DH * 2);
  bf16*  WqT = (bf16*)(R + (size_t)3 * BHN * LSEQ * DH * 2);
  bf16*  KpT = (bf16*)R;
  float* ao  = (float*)R;
  bf16*  lobf = (bf16*)d_out;   // d_out scratch; fully rewritten by k_ln

  k_cvth     <<<dim3(2048),                       256, 0, stream>>>(h, hbf);
  k_cvtw     <<<dim3(NQPAD / 64, 16),             256, 0, stream>>>(Wq, WqT, NQKV);
  k_cvtw     <<<dim3(DMODEL / 64, 16),            256, 0, stream>>>(Wo, WoT, DMODEL);
  k_cvtpm    <<<dim3(1),                          256, 0, stream>>>(pm, pmThi, pmTlo);
  k_gemm_qkvb<<<dim3(NQPAD / 128, 4096 / 128),    256, 0, stream>>>(hbf, WqT, qh, kh, vh, bbf);
  k_featm    <<<dim3(LSEQ / 64, BHN),             256, 0, stream>>>(qh, kh, pmThi, pmTlo, Qp, Kp);
  k_sgsolve  <<<dim3(NCHK, BHN),                  256, 0, stream>>>(Kp, Qp, bbf, Gll, Tm, KpT);
  k_scan     <<<dim3(128),                        512, 0, stream>>>(Kp, Qp, vh, Tm, Gll, KpT, lobf);
  k_gemm_out <<<dim3(DMODEL / 128, 4096 / 128),   256, 0, stream>>>(lobf, WoT, h, ao);
  k_ln       <<<dim3(4096),                       256, 0, stream>>>(ao, gam, bet, out);
}

// Round 13
// 349.159 us; speedup vs baseline: 1.4357x; 1.0298x over previous
//
#include <hip/hip_runtime.h>
#include <hip/hip_bf16.h>

// Problem constants (from reference)
#define LSEQ   2048
#define BSZN   2
#define DMODEL 1024
#define NHEAD  16
#define DH     64
#define MPROJ  256
#define PF     512   // 2*MPROJ feature dim
#define CHK    64    // chunk length
#define NCHK   32    // LSEQ/CHK
#define BHN    32    // BSZN*NHEAD
#define NQKV   3088  // NHEAD*(3*DH+1)
#define NQPAD  3200  // NQKV padded to 25*128

typedef __hip_bfloat16 bf16;
typedef short bf16x8 __attribute__((ext_vector_type(8)));
typedef float f32x4 __attribute__((ext_vector_type(4)));

#define MFMA(a, b, c) __builtin_amdgcn_mfma_f32_16x16x32_bf16(a, b, c, 0, 0, 0)

// unpack a u32 holding two bf16 (little-endian: low half = first element)
#define UNP(u, a, b) { a = __uint_as_float((unsigned)(u) << 16); b = __uint_as_float((unsigned)(u) & 0xffff0000u); }

static __device__ __forceinline__ float b2f(bf16 x) {
  unsigned short us = *(unsigned short*)&x;
  return __uint_as_float((unsigned)us << 16);
}
static __device__ __forceinline__ bf16 f2b(float x) { return __float2bfloat16(x); }
static __device__ __forceinline__ unsigned pkbf(float a, float b) {
  bf16 x = __float2bfloat16(a), y = __float2bfloat16(b);
  return ((unsigned)(*(unsigned short*)&y) << 16) | (unsigned)(*(unsigned short*)&x);
}

// async global->LDS, 16B per lane. gsrc is PER-LANE; ldst wave-uniform base.
static __device__ __forceinline__ void gl_lds16(const void* gsrc, void* ldst) {
  __builtin_amdgcn_global_load_lds(
      (const __attribute__((address_space(1))) unsigned int*)gsrc,
      (__attribute__((address_space(3))) unsigned int*)ldst, 16, 0, 0);
}

#define MEMFENCE asm volatile("" ::: "memory")
#define WAITV(n) asm volatile("s_waitcnt vmcnt(" #n ")" ::: "memory")
#define WAITLGKM asm volatile("s_waitcnt lgkmcnt(0)" ::: "memory")
#define BARRIER() __builtin_amdgcn_s_barrier()

// ---------------------------------------------------------------------------
// K0a: h (f32) -> hbf (bf16), pre-swizzled: unit u stored at u ^ (row&7).
// ---------------------------------------------------------------------------
__global__ __launch_bounds__(256)
void k_cvth(const float* __restrict__ h, bf16* __restrict__ hbf)
{
  const int gt = blockIdx.x * 256 + threadIdx.x;   // unit id, 4096*128 total
  const int r = gt >> 7, ug = gt & 127;
  const int grp = ug >> 3, u = ug & 7;
  const float4 f0 = *(const float4*)&h[(size_t)r * 1024 + grp * 64 + u * 8];
  const float4 f1 = *(const float4*)&h[(size_t)r * 1024 + grp * 64 + u * 8 + 4];
  uint4 o;
  o.x = pkbf(f0.x, f0.y); o.y = pkbf(f0.z, f0.w);
  o.z = pkbf(f1.x, f1.y); o.w = pkbf(f1.z, f1.w);
  *(uint4*)&hbf[(size_t)r * 1024 + grp * 64 + ((u ^ (r & 7)) << 3)] = o;
}

// ---------------------------------------------------------------------------
// K0b: W [1024][nsrc] f32 -> WT [gridDim.x*64][1024] bf16 transposed,
// pre-swizzled, zero-padded rows beyond nsrc.
// ---------------------------------------------------------------------------
__global__ __launch_bounds__(256)
void k_cvtw(const float* __restrict__ W, bf16* __restrict__ WT, int nsrc)
{
  __shared__ float sT[64][65];
  const int tid = threadIdx.x;
  const int n0 = blockIdx.x * 64, k0 = blockIdx.y * 64;
#pragma unroll
  for (int j = 0; j < 16; j++) {
    const int e = j * 256 + tid;
    const int r = e >> 6, c = e & 63;
    sT[r][c] = (n0 + c < nsrc) ? W[(size_t)(k0 + r) * nsrc + n0 + c] : 0.f;
  }
  __syncthreads();
#pragma unroll
  for (int j = 0; j < 2; j++) {
    const int uid = j * 256 + tid;
    const int rp = uid >> 3, u = uid & 7;
    uint4 o;
    o.x = pkbf(sT[u * 8 + 0][rp], sT[u * 8 + 1][rp]);
    o.y = pkbf(sT[u * 8 + 2][rp], sT[u * 8 + 3][rp]);
    o.z = pkbf(sT[u * 8 + 4][rp], sT[u * 8 + 5][rp]);
    o.w = pkbf(sT[u * 8 + 6][rp], sT[u * 8 + 7][rp]);
    *(uint4*)&WT[(size_t)(n0 + rp) * 1024 + k0 + ((u ^ (rp & 7)) << 3)] = o;
  }
}

// ---------------------------------------------------------------------------
// K0c: pm [64][256] f32 -> pmT hi/lo [256 n][64 d] bf16 (split compensation),
// scaled by 64^-0.25 = 2^-1.5, transposed, row-swizzled (key n&7).
// ---------------------------------------------------------------------------
__global__ __launch_bounds__(256)
void k_cvtpm(const float* __restrict__ pm, bf16* __restrict__ pmThi,
             bf16* __restrict__ pmTlo)
{
  const int n = threadIdx.x;
  float v[64];
#pragma unroll
  for (int d = 0; d < 64; d++) v[d] = pm[d * MPROJ + n] * 0.35355339059327373f;
  const int key = n & 7;
#pragma unroll
  for (int u = 0; u < 8; u++) {
    unsigned hi[4], lo[4];
#pragma unroll
    for (int j = 0; j < 4; j++) {
      const float a = v[u * 8 + j * 2], b = v[u * 8 + j * 2 + 1];
      const bf16 ah = f2b(a), bh_ = f2b(b);
      const float ar = a - b2f(ah), br = b - b2f(bh_);
      hi[j] = ((unsigned)(*(const unsigned short*)&bh_) << 16) | (unsigned)(*(const unsigned short*)&ah);
      const bf16 al = f2b(ar), bl = f2b(br);
      lo[j] = ((unsigned)(*(const unsigned short*)&bl) << 16) | (unsigned)(*(const unsigned short*)&al);
    }
    *(uint4*)&pmThi[(size_t)n * 64 + ((u ^ key) << 3)] = make_uint4(hi[0], hi[1], hi[2], hi[3]);
    *(uint4*)&pmTlo[(size_t)n * 64 + ((u ^ key) << 3)] = make_uint4(lo[0], lo[1], lo[2], lo[3]);
  }
}

// ---------------------------------------------------------------------------
// MFMA GEMM core, m97 recipe: C[128x128] tile, BK=64, 4 waves (2x2),
// SINGLE-buffered 32KB LDS staging ({stage -> sync -> MFMA -> sync} per
// K-step), 4+ blocks/CU for cross-block latency hiding.
// ---------------------------------------------------------------------------
#define GEMM_STAGE(Abase, Bbase, kt) {                                         \
  const size_t kb = (size_t)(kt) * 128;   /* byte offset of k-window */        \
  _Pragma("unroll")                                                            \
  for (int j = 0; j < 4; j++) {                                                \
    const int row = (w * 4 + j) * 8 + (lane >> 3);                             \
    gl_lds16((const char*)(Abase) + (size_t)(m0 + row) * 2048 + kb + (lane & 7) * 16, \
             &sA[(w * 4 + j) * 1024]);                                         \
  }                                                                            \
  _Pragma("unroll")                                                            \
  for (int j = 0; j < 4; j++) {                                                \
    const int row = (w * 4 + j) * 8 + (lane >> 3);                             \
    gl_lds16((const char*)(Bbase) + (size_t)(n0 + row) * 2048 + kb + (lane & 7) * 16, \
             &sB[(w * 4 + j) * 1024]);                                         \
  } }

#define GEMM_COMPUTE() {                                                       \
  _Pragma("unroll")                                                            \
  for (int ks = 0; ks < 2; ks++) {                                             \
    bf16x8 af[4], bfr[4];                                                      \
    _Pragma("unroll")                                                          \
    for (int f = 0; f < 4; f++) {                                              \
      const int row = wm * 64 + f * 16 + l16;                                  \
      af[f] = *(const bf16x8*)&sA[row * 128 + (((ks * 4 + lg) ^ xs) << 4)];    \
    }                                                                          \
    _Pragma("unroll")                                                          \
    for (int f = 0; f < 4; f++) {                                              \
      const int row = wn * 64 + f * 16 + l16;                                  \
      bfr[f] = *(const bf16x8*)&sB[row * 128 + (((ks * 4 + lg) ^ xs) << 4)];   \
    }                                                                          \
    _Pragma("unroll")                                                          \
    for (int fm = 0; fm < 4; fm++)                                             \
      _Pragma("unroll")                                                        \
      for (int fn = 0; fn < 4; fn++)                                           \
        acc[fm][fn] = MFMA(af[fm], bfr[fn], acc[fm][fn]);                      \
  } }

#define GEMM_PREAMBLE                                                          \
  __shared__ __align__(16) char sA[16384];                                     \
  __shared__ __align__(16) char sB[16384];                                     \
  const int tid = threadIdx.x, w = tid >> 6, lane = tid & 63;                  \
  const int l16 = lane & 15, lg = lane >> 4;                                   \
  const int wm = w >> 1, wn = w & 1;                                           \
  const int m0 = blockIdx.y * 128, n0 = blockIdx.x * 128;                      \
  const int xs = l16 & 7;                                                      \
  f32x4 acc[4][4];                                                             \
  _Pragma("unroll")                                                            \
  for (int i = 0; i < 4; i++)                                                  \
    _Pragma("unroll")                                                          \
    for (int j = 0; j < 4; j++) acc[i][j] = (f32x4){0.f, 0.f, 0.f, 0.f};

#define GEMM_LOOP(Abase, Bbase)                                                \
  for (int kt = 0; kt < 16; kt++) {                                            \
    GEMM_STAGE(Abase, Bbase, kt);                                              \
    __syncthreads();                                                           \
    GEMM_COMPUTE();                                                            \
    __syncthreads();                                                           \
  }

// K1: qkvb = hbf @ WqT^T, epilogue scatters to qh/kh (bf16, PRE-SWIZZLED for
// featm staging), vh (bf16, linear) + sigmoid b.
__global__ __launch_bounds__(256, 4)
void k_gemm_qkvb(const bf16* __restrict__ A, const bf16* __restrict__ B,
                 bf16* __restrict__ qh, bf16* __restrict__ kh,
                 bf16* __restrict__ vh, float* __restrict__ bbuf)
{
  GEMM_PREAMBLE
  GEMM_LOOP(A, B)
#pragma unroll
  for (int fm = 0; fm < 4; fm++)
#pragma unroll
    for (int fn = 0; fn < 4; fn++)
#pragma unroll
      for (int reg = 0; reg < 4; reg++) {
        const int m = m0 + wm * 64 + fm * 16 + lg * 4 + reg;
        const int n = n0 + wn * 64 + fn * 16 + l16;
        if (n >= NQKV) continue;
        const float v = acc[fm][fn][reg];
        const int l = m >> 1, bidx = m & 1;
        const int hd = n / 193;
        const int rem = n - hd * 193;
        const int bhi = bidx * NHEAD + hd;
        const size_t o = ((size_t)bhi * LSEQ + l) * DH;
        if (rem < 64) {
          const int d = rem;
          qh[o + ((((d >> 3) ^ (l & 7)) << 3) | (d & 7))] = f2b(v);
        } else if (rem < 128) {
          const int d = rem - 64;
          kh[o + ((((d >> 3) ^ (l & 7)) << 3) | (d & 7))] = f2b(v);
        } else if (rem < 192) {
          vh[o + rem - 128] = f2b(v);
        } else {
          bbuf[(size_t)bhi * LSEQ + l] = 1.f / (1.f + __expf(-v));
        }
      }
}

// K5a: ao = h + lobf @ WoT^T (f32 out)
__global__ __launch_bounds__(256, 4)
void k_gemm_out(const bf16* __restrict__ A, const bf16* __restrict__ B,
                const float* __restrict__ h, float* __restrict__ ao)
{
  GEMM_PREAMBLE
  GEMM_LOOP(A, B)
#pragma unroll
  for (int fm = 0; fm < 4; fm++)
#pragma unroll
    for (int fn = 0; fn < 4; fn++)
#pragma unroll
      for (int reg = 0; reg < 4; reg++) {
        const int m = m0 + wm * 64 + fm * 16 + lg * 4 + reg;
        const int n = n0 + wn * 64 + fn * 16 + l16;
        const size_t o = (size_t)m * DMODEL + n;
        ao[o] = acc[fm][fn][reg] + h[o];
      }
}

// ---------------------------------------------------------------------------
// K2 v2: FAVOR+ features, orientation-B MFMA (A = pmT, B = x rows).
// ---------------------------------------------------------------------------
__global__ __launch_bounds__(256, 2)
void k_featm(const bf16* __restrict__ qh, const bf16* __restrict__ kh,
             const bf16* __restrict__ pmThi, const bf16* __restrict__ pmTlo,
             bf16* __restrict__ Qp, bf16* __restrict__ Kp)
{
  __shared__ __align__(16) char sPM[2][32768];   // pmT hi, lo [256 n][64 d]
  __shared__ __align__(16) char sX[8192];        // 64 rows x 128 B (q, then k)

  const int tid = threadIdx.x, w = tid >> 6, lane = tid & 63;
  const int l16 = lane & 15, lg = lane >> 4;
  const int xs = l16 & 7;
  const int l0 = blockIdx.x * 64, bhi = blockIdx.y;

#pragma unroll
  for (int j = 0; j < 8; j++)
    gl_lds16((const char*)pmThi + (size_t)(w * 8 + j) * 1024 + lane * 16,
             &sPM[0][(w * 8 + j) * 1024]);
#pragma unroll
  for (int j = 0; j < 8; j++)
    gl_lds16((const char*)pmTlo + (size_t)(w * 8 + j) * 1024 + lane * 16,
             &sPM[1][(w * 8 + j) * 1024]);
  {
    const char* qb = (const char*)(qh + ((size_t)bhi * LSEQ + l0) * DH);
#pragma unroll
    for (int j = 0; j < 2; j++)
      gl_lds16(qb + (size_t)(w * 2 + j) * 1024 + lane * 16, &sX[(w * 2 + j) * 1024]);
  }
  MEMFENCE;
  WAITV(0); BARRIER();

  const int srow = w * 16 + l16;                 // seq row in block (per lane)
  const size_t gsr = (size_t)bhi * LSEQ + l0 + srow;

  for (int wh = 0; wh < 2; wh++) {
    bf16* dst = wh ? Kp : Qp;

    float hn;
    {
      const char* xrow = &sX[srow * 128];
      const uint4 a0 = *(const uint4*)&xrow[lg * 32];
      const uint4 a1 = *(const uint4*)&xrow[lg * 32 + 16];
      float f0, f1, f2, f3, f4, f5, f6, f7, a = 0.f;
      UNP(a0.x, f0, f1); UNP(a0.y, f2, f3); UNP(a0.z, f4, f5); UNP(a0.w, f6, f7);
      a = fmaf(f0, f0, a); a = fmaf(f1, f1, a); a = fmaf(f2, f2, a); a = fmaf(f3, f3, a);
      a = fmaf(f4, f4, a); a = fmaf(f5, f5, a); a = fmaf(f6, f6, a); a = fmaf(f7, f7, a);
      UNP(a1.x, f0, f1); UNP(a1.y, f2, f3); UNP(a1.z, f4, f5); UNP(a1.w, f6, f7);
      a = fmaf(f0, f0, a); a = fmaf(f1, f1, a); a = fmaf(f2, f2, a); a = fmaf(f3, f3, a);
      a = fmaf(f4, f4, a); a = fmaf(f5, f5, a); a = fmaf(f6, f6, a); a = fmaf(f7, f7, a);
      a += __shfl_xor(a, 16); a += __shfl_xor(a, 32);
      hn = a * 0.0625f;
    }

    f32x4 acc[16];
#pragma unroll
    for (int i = 0; i < 16; i++) acc[i] = (f32x4){0.f, 0.f, 0.f, 0.f};
#pragma unroll
    for (int ks = 0; ks < 2; ks++) {
      const bf16x8 bx = *(const bf16x8*)&sX[srow * 128 + (((ks * 4 + lg) ^ xs) << 4)];
#pragma unroll
      for (int mt = 0; mt < 16; mt++) {
        const bf16x8 ah = *(const bf16x8*)&sPM[0][(mt * 16 + l16) * 128 + (((ks * 4 + lg) ^ xs) << 4)];
        acc[mt] = MFMA(ah, bx, acc[mt]);
        const bf16x8 al = *(const bf16x8*)&sPM[1][(mt * 16 + l16) * 128 + (((ks * 4 + lg) ^ xs) << 4)];
        acc[mt] = MFMA(al, bx, acc[mt]);
      }
    }

    if (wh == 0) {
      BARRIER();
      const char* kb = (const char*)(kh + ((size_t)bhi * LSEQ + l0) * DH);
#pragma unroll
      for (int j = 0; j < 2; j++)
        gl_lds16(kb + (size_t)(w * 2 + j) * 1024 + lane * 16, &sX[(w * 2 + j) * 1024]);
      MEMFENCE;
    }

    float ss = 0.f;
#pragma unroll
    for (int mt = 0; mt < 16; mt++)
#pragma unroll
      for (int r = 0; r < 4; r++) {
        const float p = acc[mt][r];
        ss += __expf(p - hn) + __expf(-p - hn);
      }
    ss += __shfl_xor(ss, 16); ss += __shfl_xor(ss, 32);
    const float D = ss + 0.0512f;
    const float cc = 1e-4f / D;
    const float eo = hn + __logf(D);

    const size_t gb = gsr * PF;
    const int half = (lg & 1) * 4;
    const int ub = lg >> 1;
#pragma unroll
    for (int mt = 0; mt < 16; mt++) {
      const float v0 = __expf(acc[mt][0] - eo) + cc;
      const float v1 = __expf(acc[mt][1] - eo) + cc;
      const float v2 = __expf(acc[mt][2] - eo) + cc;
      const float v3 = __expf(acc[mt][3] - eo) + cc;
      const float n0 = __expf(-acc[mt][0] - eo) + cc;
      const float n1 = __expf(-acc[mt][1] - eo) + cc;
      const float n2 = __expf(-acc[mt][2] - eo) + cc;
      const float n3 = __expf(-acc[mt][3] - eo) + cc;
      const int u = mt * 2 + ub;
      *(uint2*)&dst[gb + ((u ^ xs) << 3) + half] = make_uint2(pkbf(v0, v1), pkbf(v2, v3));
      *(uint2*)&dst[gb + (((u + 32) ^ xs) << 3) + half] = make_uint2(pkbf(n0, n1), pkbf(n2, n3));
      __builtin_amdgcn_sched_barrier(0);
    }

    if (wh == 0) { WAITV(32); BARRIER(); }
  }
}

// ---------------------------------------------------------------------------
// K3 (MFMA): per (chunk, bh): S = Kp Kp^T, G = Qp Kp^T via mfma, KpT fused,
// T = (I + tril_strict(diag(b)S))^{-1} diag(b) by 64-lane forward subst.
// Gl is tril-INCLUSIVE, positive (out identity uses W_old).
// Round-13: occupancy 2 -> 4 blocks/CU (VGPR 56, LDS 33KB both fit).
// ---------------------------------------------------------------------------
__global__ __launch_bounds__(256, 4)
void k_sgsolve(const bf16* __restrict__ Kp, const bf16* __restrict__ Qp,
               const float* __restrict__ bbuf,
               bf16* __restrict__ Gl, bf16* __restrict__ Tm,
               bf16* __restrict__ KpT)
{
  __shared__ __align__(16) char bufK[2][8192];
  __shared__ __align__(16) char bufQ[2][8192];
  __shared__ float sS[CHK][65];
  __shared__ float sT[CHK][65];
  __shared__ float sBeta[CHK];

  const int tid = threadIdx.x, w = tid >> 6, lane = tid & 63;
  const int l16 = lane & 15, lg = lane >> 4;
  const int xs = l16 & 7;
  const int c = blockIdx.x, bhi = blockIdx.y;
  const size_t cb = ((size_t)bhi * LSEQ + (size_t)c * CHK) * PF;
  const size_t rowb = (size_t)bhi * LSEQ + (size_t)c * CHK;
  const size_t ktb = (((size_t)bhi * NCHK + c) * 512) * 64;
  const size_t sb = (((size_t)bhi * NCHK + c) * CHK) * CHK;

  if (tid < CHK) sBeta[tid] = bbuf[rowb + tid];

  f32x4 accS[4], accG[4];
#pragma unroll
  for (int i = 0; i < 4; i++) { accS[i] = (f32x4){0.f,0.f,0.f,0.f}; accG[i] = (f32x4){0.f,0.f,0.f,0.f}; }

#define SG_STAGE(win, b) {                                                     \
  _Pragma("unroll")                                                            \
  for (int j = 0; j < 2; j++) {                                                \
    const int row = w * 16 + j * 8 + (lane >> 3);                              \
    gl_lds16((const char*)(Kp + cb) + (size_t)row * 1024 + (size_t)(win) * 128 + (lane & 7) * 16, \
             &bufK[b][(w * 16 + j * 8) * 128]);                                \
  }                                                                            \
  _Pragma("unroll")                                                            \
  for (int j = 0; j < 2; j++) {                                                \
    const int row = w * 16 + j * 8 + (lane >> 3);                              \
    gl_lds16((const char*)(Qp + cb) + (size_t)row * 1024 + (size_t)(win) * 128 + (lane & 7) * 16, \
             &bufQ[b][(w * 16 + j * 8) * 128]);                                \
  } }

  SG_STAGE(0, 0);
  MEMFENCE;

  for (int win = 0; win < 8; win++) {
    const int b = win & 1;
    if (win < 7) { SG_STAGE(win + 1, b ^ 1); MEMFENCE; }
    if (win == 0)      { WAITV(4); }
    else if (win < 7)  { WAITV(6); }
    else               { WAITV(2); }
    BARRIER();

#pragma unroll
    for (int ks = 0; ks < 2; ks++) {
      const bf16x8 aK = *(const bf16x8*)&bufK[b][(16 * w + l16) * 128 + (((ks * 4 + lg) ^ xs) << 4)];
      const bf16x8 aQ = *(const bf16x8*)&bufQ[b][(16 * w + l16) * 128 + (((ks * 4 + lg) ^ xs) << 4)];
      bf16x8 bK[4];
#pragma unroll
      for (int nt = 0; nt < 4; nt++)
        bK[nt] = *(const bf16x8*)&bufK[b][(nt * 16 + l16) * 128 + (((ks * 4 + lg) ^ xs) << 4)];
#pragma unroll
      for (int nt = 0; nt < 4; nt++) {
        accS[nt] = MFMA(aK, bK[nt], accS[nt]);
        accG[nt] = MFMA(aQ, bK[nt], accG[nt]);
      }
    }

    // KpT emission for this window: KpT[p][l], p = win*64 + pl
#pragma unroll
    for (int jj = 0; jj < 2; jj++) {
      const int idx = jj * 256 + tid;
      const int pl = idx >> 3, l8 = idx & 7;
      unsigned short v[8];
#pragma unroll
      for (int j = 0; j < 8; j++) {
        const int l = l8 * 8 + j;
        v[j] = *(const unsigned short*)&bufK[b][l * 128 + (((pl >> 3) ^ (l & 7)) << 4) + (pl & 7) * 2];
      }
      uint4 o;
      o.x = ((unsigned)v[1] << 16) | v[0];
      o.y = ((unsigned)v[3] << 16) | v[2];
      o.z = ((unsigned)v[5] << 16) | v[4];
      o.w = ((unsigned)v[7] << 16) | v[6];
      const int p = win * 64 + pl;
      *(uint4*)&KpT[ktb + (size_t)p * 64 + ((l8 ^ (p & 7)) << 3)] = o;
    }
    BARRIER();
  }
#undef SG_STAGE

#pragma unroll
  for (int nt = 0; nt < 4; nt++)
#pragma unroll
    for (int reg = 0; reg < 4; reg++) {
      const int ri = 16 * w + lg * 4 + reg;
      const int cj = nt * 16 + l16;
      sS[ri][cj] = accS[nt][reg];
      Gl[sb + ri * 64 + (((cj >> 3) ^ (ri & 7)) << 3) + (cj & 7)] =
          f2b((cj <= ri) ? accG[nt][reg] : 0.f);
    }
  __syncthreads();

  if (tid < CHK) {
    const int j = tid;
    for (int i = 0; i < CHK; i++) {
      float acc = (i == j) ? 1.f : 0.f;
      for (int k = 0; k < i; k++) acc = fmaf(-sS[i][k], sT[k][j], acc);
      sT[i][j] = sBeta[i] * acc;
    }
  }
  __syncthreads();
  for (int t = tid; t < CHK * CHK; t += 256) {
    const int r = t >> 6, ccj = t & 63;
    Tm[sb + r * 64 + (((ccj >> 3) ^ (r & 7)) << 3) + (ccj & 7)] = f2b(sT[r][ccj]);
  }
}

// ---------------------------------------------------------------------------
// K4 v9 (round-12, best measured): 8 waves, LDS-staged, 3 barriers/chunk.
// ---------------------------------------------------------------------------
__global__ __launch_bounds__(512, 2)
void k_scan(const bf16* __restrict__ Kp, const bf16* __restrict__ Qp,
            const bf16* __restrict__ vh, const bf16* __restrict__ Tm,
            const bf16* __restrict__ Gl, const bf16* __restrict__ KpT,
            bf16* __restrict__ lobf)
{
  __shared__ __align__(16) char bufA[65536];
  __shared__ __align__(16) char bufB[65536];
  __shared__ __align__(16) char sWT[16384];     // W shadow [16 d][512 p] bf16
  __shared__ __align__(16) char suP[2][2048];   // upre halves [16 d][64 l]
  __shared__ __align__(16) char sUT[2048];      // U^T [16 d][64 l]
  __shared__ __align__(16) float pbuf[4][16][16];

  const int tid = threadIdx.x;
  const int w = tid >> 6, lane = tid & 63;
  const int l16 = lane & 15, lg = lane >> 4;
  const int wp = w >> 1, h = w & 1;
  const int bhi = blockIdx.x & 31, dq = blockIdx.x >> 5;
  const int bidx = bhi >> 4, hd = bhi & 15;
  const int xs = l16 & 7;
  const int trow = 16 * wp + l16;

  char* RA = bufA + w * 8192;   // rows 16wp..+16, p-half h (row stride 512 B)
  char* RB = bufB + w * 8192;   // KpT rows 64w..+64 (row stride 128 B)

  for (int i = tid; i < 4096; i += 512) ((unsigned*)sWT)[i] = 0u;

  f32x4 Wacc[4];
#pragma unroll
  for (int i = 0; i < 4; i++) Wacc[i] = (f32x4){0.f, 0.f, 0.f, 0.f};

  const size_t bh_base = (size_t)bhi * LSEQ * PF;
  const size_t tg0 = ((size_t)bhi * NCHK) * 4096;
  const size_t kt0 = ((size_t)bhi * NCHK) * (512 * 64);

  // prologue: KpT(0) -> RB, Kp(0) -> RA, full drain
  {
    const char* gt = (const char*)(KpT + kt0);
#pragma unroll
    for (int j = 0; j < 8; j++)
      gl_lds16(gt + (size_t)w * 8192 + j * 1024 + lane * 16, RB + j * 1024);
    const char* g = (const char*)(Kp + bh_base);
#pragma unroll
    for (int j = 0; j < 8; j++)
      gl_lds16(g + (size_t)(16 * wp + 2 * j + (lane >> 5)) * 1024 + h * 512 + (lane & 31) * 16,
               RA + j * 1024);
  }
  MEMFENCE;
  WAITV(0); WAITLGKM; BARRIER();

  for (int c = 0; c < NCHK; c++) {
    const size_t cb = bh_base + (size_t)c * CHK * PF;
    const bf16* TmC  = Tm + tg0 + (size_t)c * 4096;
    const bf16* GlC  = Gl + tg0 + (size_t)c * 4096;
    const char* QpC  = (const char*)(Qp + cb);
    const char* KpN  = (const char*)(Kp + cb + CHK * PF);
    const char* KpTN = (const char*)(KpT + kt0 + (size_t)(c + 1) * (512 * 64));

    // top-of-chunk register loads (h=0 only): V4, T2, Gl2
    float v0 = 0.f, v1 = 0.f, v2 = 0.f, v3 = 0.f;
    bf16x8 tf0 = {}, tf1 = {}, gf0 = {}, gf1 = {};
    if (!h) {
      const bf16* vp = vh + ((size_t)bhi * LSEQ + c * 64 + wp * 16 + lg * 4) * 64 + dq * 16 + l16;
      v0 = b2f(vp[0]);   v1 = b2f(vp[64]);
      v2 = b2f(vp[128]); v3 = b2f(vp[192]);
      tf0 = *(const bf16x8*)&TmC[trow * 64 + ((lg ^ xs) << 3)];
      tf1 = *(const bf16x8*)&TmC[trow * 64 + (((4 + lg) ^ xs) << 3)];
      gf0 = *(const bf16x8*)&GlC[trow * 64 + ((lg ^ xs) << 3)];
      gf1 = *(const bf16x8*)&GlC[trow * 64 + (((4 + lg) ^ xs) << 3)];
    }
    MEMFENCE;
    if (!h) { WAITV(8); } else { WAITV(0); }   // Kp(c) in RA ready

    // ---- ph1: partial upre = Kp(half h) * W_old ----
    f32x4 a0v = (f32x4){0.f,0.f,0.f,0.f}, a1v = (f32x4){0.f,0.f,0.f,0.f};
    bf16x8 wb[8];   // W_old B-frags (half h), HELD for ph4
#pragma unroll
    for (int ks = 0; ks < 8; ks += 2) {
      const bf16x8 aa0 = *(const bf16x8*)&RA[l16 * 512 + (((ks * 4 + lg) ^ xs) << 4)];
      wb[ks] = *(const bf16x8*)&sWT[l16 * 1024 + (((h * 32 + ks * 4 + lg) ^ xs) << 4)];
      a0v = MFMA(aa0, wb[ks], a0v);
      const bf16x8 aa1 = *(const bf16x8*)&RA[l16 * 512 + ((((ks + 1) * 4 + lg) ^ xs) << 4)];
      wb[ks + 1] = *(const bf16x8*)&sWT[l16 * 1024 + (((h * 32 + (ks + 1) * 4 + lg) ^ xs) << 4)];
      a1v = MFMA(aa1, wb[ks + 1], a1v);
    }
    // merged exchange: both halves write their suP buffer concurrently
    {
      const int l0r = 16 * wp + lg * 4;
      const int off = l16 * 128 + (((l0r >> 3) ^ xs) << 4) + (l0r & 7) * 2;
      if (h) {
        *(uint2*)&suP[1][off] =
            make_uint2(pkbf(-(a0v[0] + a1v[0]), -(a0v[1] + a1v[1])),
                       pkbf(-(a0v[2] + a1v[2]), -(a0v[3] + a1v[3])));
      } else {
        WAITV(0);   // V/T/G register loads done
        *(uint2*)&suP[0][off] =
            make_uint2(pkbf(v0 - (a0v[0] + a1v[0]), v1 - (a0v[1] + a1v[1])),
                       pkbf(v2 - (a0v[2] + a1v[2]), v3 - (a0v[3] + a1v[3])));
      }
    }
    WAITLGKM; BARRIER();  // B1: both suP halves ready; RA reads done

    // stage Qp(c) -> RA (own region)
#pragma unroll
    for (int j = 0; j < 8; j++)
      gl_lds16(QpC + (size_t)(16 * wp + 2 * j + (lane >> 5)) * 1024 + h * 512 + (lane & 31) * 16,
               RA + j * 1024);
    MEMFENCE;

    // ---- ph2: U = T*suP0 + T*suP1 (h=0 waves) ----
    if (!h) {
      f32x4 ua = (f32x4){0.f,0.f,0.f,0.f};
      ua = MFMA(tf0, *(const bf16x8*)&suP[0][l16 * 128 + ((lg ^ xs) << 4)], ua);
      ua = MFMA(tf1, *(const bf16x8*)&suP[0][l16 * 128 + (((4 + lg) ^ xs) << 4)], ua);
      ua = MFMA(tf0, *(const bf16x8*)&suP[1][l16 * 128 + ((lg ^ xs) << 4)], ua);
      ua = MFMA(tf1, *(const bf16x8*)&suP[1][l16 * 128 + (((4 + lg) ^ xs) << 4)], ua);
      const int l0r = 16 * wp + lg * 4;
      *(uint2*)&sUT[l16 * 128 + (((l0r >> 3) ^ xs) << 4) + (l0r & 7) * 2] =
          make_uint2(pkbf(ua[0], ua[1]), pkbf(ua[2], ua[3]));
    }
    WAITLGKM; BARRIER();  // B2: sUT ready

    // ---- ph3: Wacc += KpT(p-strip) * U ----
    const bf16x8 bu0 = *(const bf16x8*)&sUT[l16 * 128 + ((lg ^ xs) << 4)];
    const bf16x8 bu1 = *(const bf16x8*)&sUT[l16 * 128 + (((4 + lg) ^ xs) << 4)];
#pragma unroll
    for (int mt = 0; mt < 4; mt++) {
      const int pr = mt * 16 + l16;
      const bf16x8 ka0 = *(const bf16x8*)&RB[pr * 128 + ((lg ^ xs) << 4)];
      Wacc[mt] = MFMA(ka0, bu0, Wacc[mt]);
      const bf16x8 ka1 = *(const bf16x8*)&RB[pr * 128 + (((4 + lg) ^ xs) << 4)];
      Wacc[mt] = MFMA(ka1, bu1, Wacc[mt]);
    }
    WAITLGKM;   // RB reads drained before overwrite
    if (c < NCHK - 1) {
#pragma unroll
      for (int j = 0; j < 8; j++)
        gl_lds16(KpTN + (size_t)w * 8192 + j * 1024 + lane * 16, RB + j * 1024);
      MEMFENCE;
    }
    // sWT <- bf16(W_new); readers are next chunk's ph1 (after B4)
#pragma unroll
    for (int mt = 0; mt < 4; mt++) {
      const int p0m = w * 64 + mt * 16 + lg * 4;
      *(uint2*)&sWT[l16 * 1024 + (((p0m >> 3) ^ xs) << 4) + (p0m & 7) * 2] =
          make_uint2(pkbf(Wacc[mt][0], Wacc[mt][1]), pkbf(Wacc[mt][2], Wacc[mt][3]));
    }

    // ---- ph4: partial out = Qp(half h) * W_old (wb regs) ----
    if (c < NCHK - 1) { WAITV(8); } else { WAITV(0); }   // Qp ready
    f32x4 o0 = (f32x4){0.f,0.f,0.f,0.f}, o1 = (f32x4){0.f,0.f,0.f,0.f};
#pragma unroll
    for (int ks = 0; ks < 8; ks += 2) {
      const bf16x8 qa0 = *(const bf16x8*)&RA[l16 * 512 + (((ks * 4 + lg) ^ xs) << 4)];
      o0 = MFMA(qa0, wb[ks], o0);
      const bf16x8 qa1 = *(const bf16x8*)&RA[l16 * 512 + ((((ks + 1) * 4 + lg) ^ xs) << 4)];
      o1 = MFMA(qa1, wb[ks + 1], o1);
    }
    WAITLGKM;   // RA reads drained before overwrite
    if (c < NCHK - 1) {
#pragma unroll
      for (int j = 0; j < 8; j++)
        gl_lds16(KpN + (size_t)(16 * wp + 2 * j + (lane >> 5)) * 1024 + h * 512 + (lane & 31) * 16,
                 RA + j * 1024);
      MEMFENCE;
    }
    if (h) {
      float4 pv;
      pv.x = o0[0] + o1[0]; pv.y = o0[1] + o1[1];
      pv.z = o0[2] + o1[2]; pv.w = o0[3] + o1[3];
      *(float4*)&pbuf[wp][l16][lg * 4] = pv;
    } else {
      o0 = MFMA(gf0, bu0, o0);   // + Gl * U (tril-inclusive, positive)
      o1 = MFMA(gf1, bu1, o1);
    }
    WAITLGKM; BARRIER();  // B4: out partials + sWT(new) ready

    if (!h) {
      const float4 po = *(const float4*)&pbuf[wp][l16][lg * 4];
      const float pr4[4] = {po.x, po.y, po.z, po.w};
      const int colb = hd * 64 + dq * 16 + l16;
#pragma unroll
      for (int reg = 0; reg < 4; reg++) {
        const int l = c * 64 + 16 * wp + lg * 4 + reg;
        const int r = l * BSZN + bidx;
        const int cp = (colb & ~63) | ((((colb >> 3) & 7) ^ (r & 7)) << 3) | (colb & 7);
        lobf[(size_t)r * DMODEL + cp] = f2b(0.125f * (o0[reg] + o1[reg] + pr4[reg]));
      }
    }
  }
}

// ---------------------------------------------------------------------------
// K5b: LayerNorm (unchanged)
// ---------------------------------------------------------------------------
__global__ __launch_bounds__(256)
void k_ln(const float* __restrict__ ao, const float* __restrict__ gamma,
          const float* __restrict__ beta, float* __restrict__ out)
{
  const int row = blockIdx.x;
  const int tid = threadIdx.x;
  __shared__ float r1[4], r2[4];
  const float4 v = *(const float4*)&ao[(size_t)row * DMODEL + tid * 4];
  float s1 = v.x + v.y + v.z + v.w;
  float s2 = v.x * v.x + v.y * v.y + v.z * v.z + v.w * v.w;
  for (int off = 32; off > 0; off >>= 1) {
    s1 += __shfl_down(s1, off);
    s2 += __shfl_down(s2, off);
  }
  if ((tid & 63) == 0) { r1[tid >> 6] = s1; r2[tid >> 6] = s2; }
  __syncthreads();
  const float ts1 = r1[0] + r1[1] + r1[2] + r1[3];
  const float ts2 = r2[0] + r2[1] + r2[2] + r2[3];
  const float mu = ts1 * (1.f / DMODEL);
  const float var = ts2 * (1.f / DMODEL) - mu * mu;
  const float rs = rsqrtf(var + 1e-5f);
  const float4 g = *(const float4*)&gamma[tid * 4];
  const float4 b = *(const float4*)&beta[tid * 4];
  float4 o;
  o.x = (v.x - mu) * rs * g.x + b.x;
  o.y = (v.y - mu) * rs * g.y + b.y;
  o.z = (v.z - mu) * rs * g.z + b.z;
  o.w = (v.w - mu) * rs * g.w + b.w;
  *(float4*)&out[(size_t)row * DMODEL + tid * 4] = o;
}

// ---------------------------------------------------------------------------
extern "C" void kernel_launch(void* const* d_in, const int* in_sizes, int n_in,
                              void* d_out, int out_size, void* d_ws, size_t ws_size,
                              hipStream_t stream)
{
  (void)in_sizes; (void)n_in; (void)out_size; (void)ws_size;
  const float* h   = (const float*)d_in[0];
  const float* Wq  = (const float*)d_in[1];
  const float* Wo  = (const float*)d_in[2];
  const float* gam = (const float*)d_in[3];
  const float* bet = (const float*)d_in[4];
  const float* pm  = (const float*)d_in[5];
  float* out = (float*)d_out;

  char* ws = (char*)d_ws;
  size_t off = 0;
  auto alloc = [&](size_t bytes) -> void* {
    void* p = ws + off;
    off += (bytes + 255) & ~(size_t)255;
    return p;
  };
  // total workspace ~= 229 MB
  bf16*  vh  = (bf16*)alloc((size_t)BHN * LSEQ * DH * 2);            //  8.4 MB
  float* bbf = (float*)alloc((size_t)BHN * LSEQ * 4);                //  0.3 MB
  bf16*  Kp  = (bf16*)alloc((size_t)BHN * LSEQ * PF * 2);            // 67.1 MB
  bf16*  Qp  = (bf16*)alloc((size_t)BHN * LSEQ * PF * 2);            // 67.1 MB
  bf16*  Tm  = (bf16*)alloc((size_t)BHN * NCHK * CHK * CHK * 2);     //  8.4 MB
  bf16*  Gll = (bf16*)alloc((size_t)BHN * NCHK * CHK * CHK * 2);     //  8.4 MB
  char*  R   = (char*)alloc((size_t)BHN * NCHK * 512 * 64 * 2);      // 67.1 MB shared
  bf16*  WoT = (bf16*)alloc((size_t)DMODEL * DMODEL * 2);            //  2.1 MB
  bf16*  pmThi = (bf16*)alloc((size_t)MPROJ * 64 * 2);               // 32 KB
  bf16*  pmTlo = (bf16*)alloc((size_t)MPROJ * 64 * 2);               // 32 KB
  // region R lifetimes:
  //  phase1 (cvt/qkvb/featm): qh(8.4) | kh(8.4) | hbf(8.4) | WqT(6.6)
  //  phase2 (sgsolve/scan):   KpT (67.1)
  //  phase3 (outgemm/ln):     ao (16.8 f32)
  bf16*  qh  = (bf16*)R;
  bf16*  kh  = (bf16*)(R + (size_t)BHN * LSEQ * DH * 2);
  bf16*  hbf = (bf16*)(R + (size_t)2 * BHN * LSEQ * DH * 2);
  bf16*  WqT = (bf16*)(R + (size_t)3 * BHN * LSEQ * DH * 2);
  bf16*  KpT = (bf16*)R;
  float* ao  = (float*)R;
  bf16*  lobf = (bf16*)d_out;   // d_out scratch; fully rewritten by k_ln

  k_cvth     <<<dim3(2048),                       256, 0, stream>>>(h, hbf);
  k_cvtw     <<<dim3(NQPAD / 64, 16),             256, 0, stream>>>(Wq, WqT, NQKV);
  k_cvtw     <<<dim3(DMODEL / 64, 16),            256, 0, stream>>>(Wo, WoT, DMODEL);
  k_cvtpm    <<<dim3(1),                          256, 0, stream>>>(pm, pmThi, pmTlo);
  k_gemm_qkvb<<<dim3(NQPAD / 128, 4096 / 128),    256, 0, stream>>>(hbf, WqT, qh, kh, vh, bbf);
  k_featm    <<<dim3(LSEQ / 64, BHN),             256, 0, stream>>>(qh, kh, pmThi, pmTlo, Qp, Kp);
  k_sgsolve  <<<dim3(NCHK, BHN),                  256, 0, stream>>>(Kp, Qp, bbf, Gll, Tm, KpT);
  k_scan     <<<dim3(128),                        512, 0, stream>>>(Kp, Qp, vh, Tm, Gll, KpT, lobf);
  k_gemm_out <<<dim3(DMODEL / 128, 4096 / 128),   256, 0, stream>>>(lobf, WoT, h, ao);
  k_ln       <<<dim3(4096),                       256, 0, stream>>>(ao, gam, bet, out);
}

// Round 14
// 336.931 us; speedup vs baseline: 1.4878x; 1.0363x over previous
//
#include <hip/hip_runtime.h>
#include <hip/hip_bf16.h>

// Problem constants (from reference)
#define LSEQ   2048
#define BSZN   2
#define DMODEL 1024
#define NHEAD  16
#define DH     64
#define MPROJ  256
#define PF     512   // 2*MPROJ feature dim
#define CHK    64    // chunk length
#define NCHK   32    // LSEQ/CHK
#define BHN    32    // BSZN*NHEAD
#define NQKV   3088  // NHEAD*(3*DH+1)
#define NQPAD  3200  // NQKV padded to 25*128

typedef __hip_bfloat16 bf16;
typedef short bf16x8 __attribute__((ext_vector_type(8)));
typedef float f32x4 __attribute__((ext_vector_type(4)));

#define MFMA(a, b, c) __builtin_amdgcn_mfma_f32_16x16x32_bf16(a, b, c, 0, 0, 0)

// unpack a u32 holding two bf16 (little-endian: low half = first element)
#define UNP(u, a, b) { a = __uint_as_float((unsigned)(u) << 16); b = __uint_as_float((unsigned)(u) & 0xffff0000u); }

static __device__ __forceinline__ float b2f(bf16 x) {
  unsigned short us = *(unsigned short*)&x;
  return __uint_as_float((unsigned)us << 16);
}
static __device__ __forceinline__ bf16 f2b(float x) { return __float2bfloat16(x); }
static __device__ __forceinline__ unsigned pkbf(float a, float b) {
  bf16 x = __float2bfloat16(a), y = __float2bfloat16(b);
  return ((unsigned)(*(unsigned short*)&y) << 16) | (unsigned)(*(unsigned short*)&x);
}

// async global->LDS, 16B per lane. gsrc is PER-LANE; ldst wave-uniform base.
static __device__ __forceinline__ void gl_lds16(const void* gsrc, void* ldst) {
  __builtin_amdgcn_global_load_lds(
      (const __attribute__((address_space(1))) unsigned int*)gsrc,
      (__attribute__((address_space(3))) unsigned int*)ldst, 16, 0, 0);
}

#define MEMFENCE asm volatile("" ::: "memory")
#define WAITV(n) asm volatile("s_waitcnt vmcnt(" #n ")" ::: "memory")
#define WAITLGKM asm volatile("s_waitcnt lgkmcnt(0)" ::: "memory")
#define BARRIER() __builtin_amdgcn_s_barrier()

// ---------------------------------------------------------------------------
// K0 (merged prep): block-range routing.
//   [0, 2048)      : h (f32) -> hbf (bf16, pre-swizzled)
//   [2048, 2848)   : Wq -> WqT (transposed bf16, swizzled, padded to 3200)
//   [2848, 3104)   : Wo -> WoT
//   3104           : pm -> pmT hi/lo (split compensation, scaled 2^-1.5)
// ---------------------------------------------------------------------------
__global__ __launch_bounds__(256)
void k_prep(const float* __restrict__ h, bf16* __restrict__ hbf,
            const float* __restrict__ Wq, bf16* __restrict__ WqT,
            const float* __restrict__ Wo, bf16* __restrict__ WoT,
            const float* __restrict__ pm, bf16* __restrict__ pmThi,
            bf16* __restrict__ pmTlo)
{
  const int b = blockIdx.x;
  const int tid = threadIdx.x;

  if (b < 2048) {               // ---- cvth ----
    const int gt = b * 256 + tid;
    const int r = gt >> 7, ug = gt & 127;
    const int grp = ug >> 3, u = ug & 7;
    const float4 f0 = *(const float4*)&h[(size_t)r * 1024 + grp * 64 + u * 8];
    const float4 f1 = *(const float4*)&h[(size_t)r * 1024 + grp * 64 + u * 8 + 4];
    uint4 o;
    o.x = pkbf(f0.x, f0.y); o.y = pkbf(f0.z, f0.w);
    o.z = pkbf(f1.x, f1.y); o.w = pkbf(f1.z, f1.w);
    *(uint4*)&hbf[(size_t)r * 1024 + grp * 64 + ((u ^ (r & 7)) << 3)] = o;
    return;
  }

  if (b == 3104) {              // ---- cvtpm ----
    const int n = tid;
    float v[64];
#pragma unroll
    for (int d = 0; d < 64; d++) v[d] = pm[d * MPROJ + n] * 0.35355339059327373f;
    const int key = n & 7;
#pragma unroll
    for (int u = 0; u < 8; u++) {
      unsigned hi[4], lo[4];
#pragma unroll
      for (int j = 0; j < 4; j++) {
        const float a = v[u * 8 + j * 2], bb = v[u * 8 + j * 2 + 1];
        const bf16 ah = f2b(a), bh_ = f2b(bb);
        const float ar = a - b2f(ah), br = bb - b2f(bh_);
        hi[j] = ((unsigned)(*(const unsigned short*)&bh_) << 16) | (unsigned)(*(const unsigned short*)&ah);
        const bf16 al = f2b(ar), bl = f2b(br);
        lo[j] = ((unsigned)(*(const unsigned short*)&bl) << 16) | (unsigned)(*(const unsigned short*)&al);
      }
      *(uint4*)&pmThi[(size_t)n * 64 + ((u ^ key) << 3)] = make_uint4(hi[0], hi[1], hi[2], hi[3]);
      *(uint4*)&pmTlo[(size_t)n * 64 + ((u ^ key) << 3)] = make_uint4(lo[0], lo[1], lo[2], lo[3]);
    }
    return;
  }

  // ---- cvtw (Wq or Wo) ----
  __shared__ float sT[64][65];
  const float* W;
  bf16* WT;
  int nsrc, n0, k0;
  if (b < 2848) {
    const int idx = b - 2048;
    W = Wq; WT = WqT; nsrc = NQKV;
    n0 = (idx % 50) * 64; k0 = (idx / 50) * 64;
  } else {
    const int idx = b - 2848;
    W = Wo; WT = WoT; nsrc = DMODEL;
    n0 = (idx % 16) * 64; k0 = (idx / 16) * 64;
  }
#pragma unroll
  for (int j = 0; j < 16; j++) {
    const int e = j * 256 + tid;
    const int r = e >> 6, c = e & 63;
    sT[r][c] = (n0 + c < nsrc) ? W[(size_t)(k0 + r) * nsrc + n0 + c] : 0.f;
  }
  __syncthreads();
#pragma unroll
  for (int j = 0; j < 2; j++) {
    const int uid = j * 256 + tid;
    const int rp = uid >> 3, u = uid & 7;
    uint4 o;
    o.x = pkbf(sT[u * 8 + 0][rp], sT[u * 8 + 1][rp]);
    o.y = pkbf(sT[u * 8 + 2][rp], sT[u * 8 + 3][rp]);
    o.z = pkbf(sT[u * 8 + 4][rp], sT[u * 8 + 5][rp]);
    o.w = pkbf(sT[u * 8 + 6][rp], sT[u * 8 + 7][rp]);
    *(uint4*)&WT[(size_t)(n0 + rp) * 1024 + k0 + ((u ^ (rp & 7)) << 3)] = o;
  }
}

// ---------------------------------------------------------------------------
// MFMA GEMM core, m97 recipe: C[128x128] tile, BK=64, 4 waves (2x2),
// SINGLE-buffered 32KB LDS staging, 4 blocks/CU for cross-block hiding.
// ---------------------------------------------------------------------------
#define GEMM_STAGE(Abase, Bbase, kt) {                                         \
  const size_t kb = (size_t)(kt) * 128;   /* byte offset of k-window */        \
  _Pragma("unroll")                                                            \
  for (int j = 0; j < 4; j++) {                                                \
    const int row = (w * 4 + j) * 8 + (lane >> 3);                             \
    gl_lds16((const char*)(Abase) + (size_t)(m0 + row) * 2048 + kb + (lane & 7) * 16, \
             &sA[(w * 4 + j) * 1024]);                                         \
  }                                                                            \
  _Pragma("unroll")                                                            \
  for (int j = 0; j < 4; j++) {                                                \
    const int row = (w * 4 + j) * 8 + (lane >> 3);                             \
    gl_lds16((const char*)(Bbase) + (size_t)(n0 + row) * 2048 + kb + (lane & 7) * 16, \
             &sB[(w * 4 + j) * 1024]);                                         \
  } }

#define GEMM_COMPUTE() {                                                       \
  _Pragma("unroll")                                                            \
  for (int ks = 0; ks < 2; ks++) {                                             \
    bf16x8 af[4], bfr[4];                                                      \
    _Pragma("unroll")                                                          \
    for (int f = 0; f < 4; f++) {                                              \
      const int row = wm * 64 + f * 16 + l16;                                  \
      af[f] = *(const bf16x8*)&sA[row * 128 + (((ks * 4 + lg) ^ xs) << 4)];    \
    }                                                                          \
    _Pragma("unroll")                                                          \
    for (int f = 0; f < 4; f++) {                                              \
      const int row = wn * 64 + f * 16 + l16;                                  \
      bfr[f] = *(const bf16x8*)&sB[row * 128 + (((ks * 4 + lg) ^ xs) << 4)];   \
    }                                                                          \
    _Pragma("unroll")                                                          \
    for (int fm = 0; fm < 4; fm++)                                             \
      _Pragma("unroll")                                                        \
      for (int fn = 0; fn < 4; fn++)                                           \
        acc[fm][fn] = MFMA(af[fm], bfr[fn], acc[fm][fn]);                      \
  } }

#define GEMM_PREAMBLE                                                          \
  __shared__ __align__(16) char sA[16384];                                     \
  __shared__ __align__(16) char sB[16384];                                     \
  const int tid = threadIdx.x, w = tid >> 6, lane = tid & 63;                  \
  const int l16 = lane & 15, lg = lane >> 4;                                   \
  const int wm = w >> 1, wn = w & 1;                                           \
  const int m0 = blockIdx.y * 128, n0 = blockIdx.x * 128;                      \
  const int xs = l16 & 7;                                                      \
  f32x4 acc[4][4];                                                             \
  _Pragma("unroll")                                                            \
  for (int i = 0; i < 4; i++)                                                  \
    _Pragma("unroll")                                                          \
    for (int j = 0; j < 4; j++) acc[i][j] = (f32x4){0.f, 0.f, 0.f, 0.f};

#define GEMM_LOOP(Abase, Bbase)                                                \
  for (int kt = 0; kt < 16; kt++) {                                            \
    GEMM_STAGE(Abase, Bbase, kt);                                              \
    __syncthreads();                                                           \
    GEMM_COMPUTE();                                                            \
    __syncthreads();                                                           \
  }

// K1: qkvb = hbf @ WqT^T, epilogue scatters to qh/kh (bf16, PRE-SWIZZLED for
// featm staging), vh (bf16, linear) + sigmoid b.
__global__ __launch_bounds__(256, 4)
void k_gemm_qkvb(const bf16* __restrict__ A, const bf16* __restrict__ B,
                 bf16* __restrict__ qh, bf16* __restrict__ kh,
                 bf16* __restrict__ vh, float* __restrict__ bbuf)
{
  GEMM_PREAMBLE
  GEMM_LOOP(A, B)
#pragma unroll
  for (int fm = 0; fm < 4; fm++)
#pragma unroll
    for (int fn = 0; fn < 4; fn++)
#pragma unroll
      for (int reg = 0; reg < 4; reg++) {
        const int m = m0 + wm * 64 + fm * 16 + lg * 4 + reg;
        const int n = n0 + wn * 64 + fn * 16 + l16;
        if (n >= NQKV) continue;
        const float v = acc[fm][fn][reg];
        const int l = m >> 1, bidx = m & 1;
        const int hd = n / 193;
        const int rem = n - hd * 193;
        const int bhi = bidx * NHEAD + hd;
        const size_t o = ((size_t)bhi * LSEQ + l) * DH;
        if (rem < 64) {
          const int d = rem;
          qh[o + ((((d >> 3) ^ (l & 7)) << 3) | (d & 7))] = f2b(v);
        } else if (rem < 128) {
          const int d = rem - 64;
          kh[o + ((((d >> 3) ^ (l & 7)) << 3) | (d & 7))] = f2b(v);
        } else if (rem < 192) {
          vh[o + rem - 128] = f2b(v);
        } else {
          bbuf[(size_t)bhi * LSEQ + l] = 1.f / (1.f + __expf(-v));
        }
      }
}

// K5a: ao = h + lobf @ WoT^T (f32 out)
__global__ __launch_bounds__(256, 4)
void k_gemm_out(const bf16* __restrict__ A, const bf16* __restrict__ B,
                const float* __restrict__ h, float* __restrict__ ao)
{
  GEMM_PREAMBLE
  GEMM_LOOP(A, B)
#pragma unroll
  for (int fm = 0; fm < 4; fm++)
#pragma unroll
    for (int fn = 0; fn < 4; fn++)
#pragma unroll
      for (int reg = 0; reg < 4; reg++) {
        const int m = m0 + wm * 64 + fm * 16 + lg * 4 + reg;
        const int n = n0 + wn * 64 + fn * 16 + l16;
        const size_t o = (size_t)m * DMODEL + n;
        ao[o] = acc[fm][fn][reg] + h[o];
      }
}

// ---------------------------------------------------------------------------
// K2 v2: FAVOR+ features, orientation-B MFMA (A = pmT, B = x rows).
// ---------------------------------------------------------------------------
__global__ __launch_bounds__(256, 2)
void k_featm(const bf16* __restrict__ qh, const bf16* __restrict__ kh,
             const bf16* __restrict__ pmThi, const bf16* __restrict__ pmTlo,
             bf16* __restrict__ Qp, bf16* __restrict__ Kp)
{
  __shared__ __align__(16) char sPM[2][32768];   // pmT hi, lo [256 n][64 d]
  __shared__ __align__(16) char sX[8192];        // 64 rows x 128 B (q, then k)

  const int tid = threadIdx.x, w = tid >> 6, lane = tid & 63;
  const int l16 = lane & 15, lg = lane >> 4;
  const int xs = l16 & 7;
  const int l0 = blockIdx.x * 64, bhi = blockIdx.y;

#pragma unroll
  for (int j = 0; j < 8; j++)
    gl_lds16((const char*)pmThi + (size_t)(w * 8 + j) * 1024 + lane * 16,
             &sPM[0][(w * 8 + j) * 1024]);
#pragma unroll
  for (int j = 0; j < 8; j++)
    gl_lds16((const char*)pmTlo + (size_t)(w * 8 + j) * 1024 + lane * 16,
             &sPM[1][(w * 8 + j) * 1024]);
  {
    const char* qb = (const char*)(qh + ((size_t)bhi * LSEQ + l0) * DH);
#pragma unroll
    for (int j = 0; j < 2; j++)
      gl_lds16(qb + (size_t)(w * 2 + j) * 1024 + lane * 16, &sX[(w * 2 + j) * 1024]);
  }
  MEMFENCE;
  WAITV(0); BARRIER();

  const int srow = w * 16 + l16;                 // seq row in block (per lane)
  const size_t gsr = (size_t)bhi * LSEQ + l0 + srow;

  for (int wh = 0; wh < 2; wh++) {
    bf16* dst = wh ? Kp : Qp;

    float hn;
    {
      const char* xrow = &sX[srow * 128];
      const uint4 a0 = *(const uint4*)&xrow[lg * 32];
      const uint4 a1 = *(const uint4*)&xrow[lg * 32 + 16];
      float f0, f1, f2, f3, f4, f5, f6, f7, a = 0.f;
      UNP(a0.x, f0, f1); UNP(a0.y, f2, f3); UNP(a0.z, f4, f5); UNP(a0.w, f6, f7);
      a = fmaf(f0, f0, a); a = fmaf(f1, f1, a); a = fmaf(f2, f2, a); a = fmaf(f3, f3, a);
      a = fmaf(f4, f4, a); a = fmaf(f5, f5, a); a = fmaf(f6, f6, a); a = fmaf(f7, f7, a);
      UNP(a1.x, f0, f1); UNP(a1.y, f2, f3); UNP(a1.z, f4, f5); UNP(a1.w, f6, f7);
      a = fmaf(f0, f0, a); a = fmaf(f1, f1, a); a = fmaf(f2, f2, a); a = fmaf(f3, f3, a);
      a = fmaf(f4, f4, a); a = fmaf(f5, f5, a); a = fmaf(f6, f6, a); a = fmaf(f7, f7, a);
      a += __shfl_xor(a, 16); a += __shfl_xor(a, 32);
      hn = a * 0.0625f;
    }

    f32x4 acc[16];
#pragma unroll
    for (int i = 0; i < 16; i++) acc[i] = (f32x4){0.f, 0.f, 0.f, 0.f};
#pragma unroll
    for (int ks = 0; ks < 2; ks++) {
      const bf16x8 bx = *(const bf16x8*)&sX[srow * 128 + (((ks * 4 + lg) ^ xs) << 4)];
#pragma unroll
      for (int mt = 0; mt < 16; mt++) {
        const bf16x8 ah = *(const bf16x8*)&sPM[0][(mt * 16 + l16) * 128 + (((ks * 4 + lg) ^ xs) << 4)];
        acc[mt] = MFMA(ah, bx, acc[mt]);
        const bf16x8 al = *(const bf16x8*)&sPM[1][(mt * 16 + l16) * 128 + (((ks * 4 + lg) ^ xs) << 4)];
        acc[mt] = MFMA(al, bx, acc[mt]);
      }
    }

    if (wh == 0) {
      BARRIER();
      const char* kb = (const char*)(kh + ((size_t)bhi * LSEQ + l0) * DH);
#pragma unroll
      for (int j = 0; j < 2; j++)
        gl_lds16(kb + (size_t)(w * 2 + j) * 1024 + lane * 16, &sX[(w * 2 + j) * 1024]);
      MEMFENCE;
    }

    float ss = 0.f;
#pragma unroll
    for (int mt = 0; mt < 16; mt++)
#pragma unroll
      for (int r = 0; r < 4; r++) {
        const float p = acc[mt][r];
        ss += __expf(p - hn) + __expf(-p - hn);
      }
    ss += __shfl_xor(ss, 16); ss += __shfl_xor(ss, 32);
    const float D = ss + 0.0512f;
    const float cc = 1e-4f / D;
    const float eo = hn + __logf(D);

    const size_t gb = gsr * PF;
    const int half = (lg & 1) * 4;
    const int ub = lg >> 1;
#pragma unroll
    for (int mt = 0; mt < 16; mt++) {
      const float v0 = __expf(acc[mt][0] - eo) + cc;
      const float v1 = __expf(acc[mt][1] - eo) + cc;
      const float v2 = __expf(acc[mt][2] - eo) + cc;
      const float v3 = __expf(acc[mt][3] - eo) + cc;
      const float n0 = __expf(-acc[mt][0] - eo) + cc;
      const float n1 = __expf(-acc[mt][1] - eo) + cc;
      const float n2 = __expf(-acc[mt][2] - eo) + cc;
      const float n3 = __expf(-acc[mt][3] - eo) + cc;
      const int u = mt * 2 + ub;
      *(uint2*)&dst[gb + ((u ^ xs) << 3) + half] = make_uint2(pkbf(v0, v1), pkbf(v2, v3));
      *(uint2*)&dst[gb + (((u + 32) ^ xs) << 3) + half] = make_uint2(pkbf(n0, n1), pkbf(n2, n3));
      __builtin_amdgcn_sched_barrier(0);
    }

    if (wh == 0) { WAITV(32); BARRIER(); }
  }
}

// ---------------------------------------------------------------------------
// K3 (MFMA): per (chunk, bh): S = Kp Kp^T, G = Qp Kp^T via mfma, KpT fused,
// T = (I + tril_strict(diag(b)S))^{-1} diag(b) by 64-lane forward subst.
// Gl is tril-INCLUSIVE, positive (out identity uses W_old).
// ---------------------------------------------------------------------------
__global__ __launch_bounds__(256, 4)
void k_sgsolve(const bf16* __restrict__ Kp, const bf16* __restrict__ Qp,
               const float* __restrict__ bbuf,
               bf16* __restrict__ Gl, bf16* __restrict__ Tm,
               bf16* __restrict__ KpT)
{
  __shared__ __align__(16) char bufK[2][8192];
  __shared__ __align__(16) char bufQ[2][8192];
  __shared__ float sS[CHK][65];
  __shared__ float sT[CHK][65];
  __shared__ float sBeta[CHK];

  const int tid = threadIdx.x, w = tid >> 6, lane = tid & 63;
  const int l16 = lane & 15, lg = lane >> 4;
  const int xs = l16 & 7;
  const int c = blockIdx.x, bhi = blockIdx.y;
  const size_t cb = ((size_t)bhi * LSEQ + (size_t)c * CHK) * PF;
  const size_t rowb = (size_t)bhi * LSEQ + (size_t)c * CHK;
  const size_t ktb = (((size_t)bhi * NCHK + c) * 512) * 64;
  const size_t sb = (((size_t)bhi * NCHK + c) * CHK) * CHK;

  if (tid < CHK) sBeta[tid] = bbuf[rowb + tid];

  f32x4 accS[4], accG[4];
#pragma unroll
  for (int i = 0; i < 4; i++) { accS[i] = (f32x4){0.f,0.f,0.f,0.f}; accG[i] = (f32x4){0.f,0.f,0.f,0.f}; }

#define SG_STAGE(win, b) {                                                     \
  _Pragma("unroll")                                                            \
  for (int j = 0; j < 2; j++) {                                                \
    const int row = w * 16 + j * 8 + (lane >> 3);                              \
    gl_lds16((const char*)(Kp + cb) + (size_t)row * 1024 + (size_t)(win) * 128 + (lane & 7) * 16, \
             &bufK[b][(w * 16 + j * 8) * 128]);                                \
  }                                                                            \
  _Pragma("unroll")                                                            \
  for (int j = 0; j < 2; j++) {                                                \
    const int row = w * 16 + j * 8 + (lane >> 3);                              \
    gl_lds16((const char*)(Qp + cb) + (size_t)row * 1024 + (size_t)(win) * 128 + (lane & 7) * 16, \
             &bufQ[b][(w * 16 + j * 8) * 128]);                                \
  } }

  SG_STAGE(0, 0);
  MEMFENCE;

  for (int win = 0; win < 8; win++) {
    const int b = win & 1;
    if (win < 7) { SG_STAGE(win + 1, b ^ 1); MEMFENCE; }
    if (win == 0)      { WAITV(4); }
    else if (win < 7)  { WAITV(6); }
    else               { WAITV(2); }
    BARRIER();

#pragma unroll
    for (int ks = 0; ks < 2; ks++) {
      const bf16x8 aK = *(const bf16x8*)&bufK[b][(16 * w + l16) * 128 + (((ks * 4 + lg) ^ xs) << 4)];
      const bf16x8 aQ = *(const bf16x8*)&bufQ[b][(16 * w + l16) * 128 + (((ks * 4 + lg) ^ xs) << 4)];
      bf16x8 bK[4];
#pragma unroll
      for (int nt = 0; nt < 4; nt++)
        bK[nt] = *(const bf16x8*)&bufK[b][(nt * 16 + l16) * 128 + (((ks * 4 + lg) ^ xs) << 4)];
#pragma unroll
      for (int nt = 0; nt < 4; nt++) {
        accS[nt] = MFMA(aK, bK[nt], accS[nt]);
        accG[nt] = MFMA(aQ, bK[nt], accG[nt]);
      }
    }

    // KpT emission for this window: KpT[p][l], p = win*64 + pl
#pragma unroll
    for (int jj = 0; jj < 2; jj++) {
      const int idx = jj * 256 + tid;
      const int pl = idx >> 3, l8 = idx & 7;
      unsigned short v[8];
#pragma unroll
      for (int j = 0; j < 8; j++) {
        const int l = l8 * 8 + j;
        v[j] = *(const unsigned short*)&bufK[b][l * 128 + (((pl >> 3) ^ (l & 7)) << 4) + (pl & 7) * 2];
      }
      uint4 o;
      o.x = ((unsigned)v[1] << 16) | v[0];
      o.y = ((unsigned)v[3] << 16) | v[2];
      o.z = ((unsigned)v[5] << 16) | v[4];
      o.w = ((unsigned)v[7] << 16) | v[6];
      const int p = win * 64 + pl;
      *(uint4*)&KpT[ktb + (size_t)p * 64 + ((l8 ^ (p & 7)) << 3)] = o;
    }
    BARRIER();
  }
#undef SG_STAGE

#pragma unroll
  for (int nt = 0; nt < 4; nt++)
#pragma unroll
    for (int reg = 0; reg < 4; reg++) {
      const int ri = 16 * w + lg * 4 + reg;
      const int cj = nt * 16 + l16;
      sS[ri][cj] = accS[nt][reg];
      Gl[sb + ri * 64 + (((cj >> 3) ^ (ri & 7)) << 3) + (cj & 7)] =
          f2b((cj <= ri) ? accG[nt][reg] : 0.f);
    }
  __syncthreads();

  if (tid < CHK) {
    const int j = tid;
    for (int i = 0; i < CHK; i++) {
      float acc = (i == j) ? 1.f : 0.f;
      for (int k = 0; k < i; k++) acc = fmaf(-sS[i][k], sT[k][j], acc);
      sT[i][j] = sBeta[i] * acc;
    }
  }
  __syncthreads();
  for (int t = tid; t < CHK * CHK; t += 256) {
    const int r = t >> 6, ccj = t & 63;
    Tm[sb + r * 64 + (((ccj >> 3) ^ (r & 7)) << 3) + (ccj & 7)] = f2b(sT[r][ccj]);
  }
}

// ---------------------------------------------------------------------------
// K4 v9 (round-12/13, best measured): 8 waves, LDS-staged, 3 barriers/chunk.
// ---------------------------------------------------------------------------
__global__ __launch_bounds__(512, 2)
void k_scan(const bf16* __restrict__ Kp, const bf16* __restrict__ Qp,
            const bf16* __restrict__ vh, const bf16* __restrict__ Tm,
            const bf16* __restrict__ Gl, const bf16* __restrict__ KpT,
            bf16* __restrict__ lobf)
{
  __shared__ __align__(16) char bufA[65536];
  __shared__ __align__(16) char bufB[65536];
  __shared__ __align__(16) char sWT[16384];     // W shadow [16 d][512 p] bf16
  __shared__ __align__(16) char suP[2][2048];   // upre halves [16 d][64 l]
  __shared__ __align__(16) char sUT[2048];      // U^T [16 d][64 l]
  __shared__ __align__(16) float pbuf[4][16][16];

  const int tid = threadIdx.x;
  const int w = tid >> 6, lane = tid & 63;
  const int l16 = lane & 15, lg = lane >> 4;
  const int wp = w >> 1, h = w & 1;
  const int bhi = blockIdx.x & 31, dq = blockIdx.x >> 5;
  const int bidx = bhi >> 4, hd = bhi & 15;
  const int xs = l16 & 7;
  const int trow = 16 * wp + l16;

  char* RA = bufA + w * 8192;   // rows 16wp..+16, p-half h (row stride 512 B)
  char* RB = bufB + w * 8192;   // KpT rows 64w..+64 (row stride 128 B)

  for (int i = tid; i < 4096; i += 512) ((unsigned*)sWT)[i] = 0u;

  f32x4 Wacc[4];
#pragma unroll
  for (int i = 0; i < 4; i++) Wacc[i] = (f32x4){0.f, 0.f, 0.f, 0.f};

  const size_t bh_base = (size_t)bhi * LSEQ * PF;
  const size_t tg0 = ((size_t)bhi * NCHK) * 4096;
  const size_t kt0 = ((size_t)bhi * NCHK) * (512 * 64);

  // prologue: KpT(0) -> RB, Kp(0) -> RA, full drain
  {
    const char* gt = (const char*)(KpT + kt0);
#pragma unroll
    for (int j = 0; j < 8; j++)
      gl_lds16(gt + (size_t)w * 8192 + j * 1024 + lane * 16, RB + j * 1024);
    const char* g = (const char*)(Kp + bh_base);
#pragma unroll
    for (int j = 0; j < 8; j++)
      gl_lds16(g + (size_t)(16 * wp + 2 * j + (lane >> 5)) * 1024 + h * 512 + (lane & 31) * 16,
               RA + j * 1024);
  }
  MEMFENCE;
  WAITV(0); WAITLGKM; BARRIER();

  for (int c = 0; c < NCHK; c++) {
    const size_t cb = bh_base + (size_t)c * CHK * PF;
    const bf16* TmC  = Tm + tg0 + (size_t)c * 4096;
    const bf16* GlC  = Gl + tg0 + (size_t)c * 4096;
    const char* QpC  = (const char*)(Qp + cb);
    const char* KpN  = (const char*)(Kp + cb + CHK * PF);
    const char* KpTN = (const char*)(KpT + kt0 + (size_t)(c + 1) * (512 * 64));

    // top-of-chunk register loads (h=0 only): V4, T2, Gl2
    float v0 = 0.f, v1 = 0.f, v2 = 0.f, v3 = 0.f;
    bf16x8 tf0 = {}, tf1 = {}, gf0 = {}, gf1 = {};
    if (!h) {
      const bf16* vp = vh + ((size_t)bhi * LSEQ + c * 64 + wp * 16 + lg * 4) * 64 + dq * 16 + l16;
      v0 = b2f(vp[0]);   v1 = b2f(vp[64]);
      v2 = b2f(vp[128]); v3 = b2f(vp[192]);
      tf0 = *(const bf16x8*)&TmC[trow * 64 + ((lg ^ xs) << 3)];
      tf1 = *(const bf16x8*)&TmC[trow * 64 + (((4 + lg) ^ xs) << 3)];
      gf0 = *(const bf16x8*)&GlC[trow * 64 + ((lg ^ xs) << 3)];
      gf1 = *(const bf16x8*)&GlC[trow * 64 + (((4 + lg) ^ xs) << 3)];
    }
    MEMFENCE;
    if (!h) { WAITV(8); } else { WAITV(0); }   // Kp(c) in RA ready

    // ---- ph1: partial upre = Kp(half h) * W_old ----
    f32x4 a0v = (f32x4){0.f,0.f,0.f,0.f}, a1v = (f32x4){0.f,0.f,0.f,0.f};
    bf16x8 wb[8];   // W_old B-frags (half h), HELD for ph4
#pragma unroll
    for (int ks = 0; ks < 8; ks += 2) {
      const bf16x8 aa0 = *(const bf16x8*)&RA[l16 * 512 + (((ks * 4 + lg) ^ xs) << 4)];
      wb[ks] = *(const bf16x8*)&sWT[l16 * 1024 + (((h * 32 + ks * 4 + lg) ^ xs) << 4)];
      a0v = MFMA(aa0, wb[ks], a0v);
      const bf16x8 aa1 = *(const bf16x8*)&RA[l16 * 512 + ((((ks + 1) * 4 + lg) ^ xs) << 4)];
      wb[ks + 1] = *(const bf16x8*)&sWT[l16 * 1024 + (((h * 32 + (ks + 1) * 4 + lg) ^ xs) << 4)];
      a1v = MFMA(aa1, wb[ks + 1], a1v);
    }
    // merged exchange: both halves write their suP buffer concurrently
    {
      const int l0r = 16 * wp + lg * 4;
      const int off = l16 * 128 + (((l0r >> 3) ^ xs) << 4) + (l0r & 7) * 2;
      if (h) {
        *(uint2*)&suP[1][off] =
            make_uint2(pkbf(-(a0v[0] + a1v[0]), -(a0v[1] + a1v[1])),
                       pkbf(-(a0v[2] + a1v[2]), -(a0v[3] + a1v[3])));
      } else {
        WAITV(0);   // V/T/G register loads done
        *(uint2*)&suP[0][off] =
            make_uint2(pkbf(v0 - (a0v[0] + a1v[0]), v1 - (a0v[1] + a1v[1])),
                       pkbf(v2 - (a0v[2] + a1v[2]), v3 - (a0v[3] + a1v[3])));
      }
    }
    WAITLGKM; BARRIER();  // B1: both suP halves ready; RA reads done

    // stage Qp(c) -> RA (own region)
#pragma unroll
    for (int j = 0; j < 8; j++)
      gl_lds16(QpC + (size_t)(16 * wp + 2 * j + (lane >> 5)) * 1024 + h * 512 + (lane & 31) * 16,
               RA + j * 1024);
    MEMFENCE;

    // ---- ph2: U = T*suP0 + T*suP1 (h=0 waves) ----
    if (!h) {
      f32x4 ua = (f32x4){0.f,0.f,0.f,0.f};
      ua = MFMA(tf0, *(const bf16x8*)&suP[0][l16 * 128 + ((lg ^ xs) << 4)], ua);
      ua = MFMA(tf1, *(const bf16x8*)&suP[0][l16 * 128 + (((4 + lg) ^ xs) << 4)], ua);
      ua = MFMA(tf0, *(const bf16x8*)&suP[1][l16 * 128 + ((lg ^ xs) << 4)], ua);
      ua = MFMA(tf1, *(const bf16x8*)&suP[1][l16 * 128 + (((4 + lg) ^ xs) << 4)], ua);
      const int l0r = 16 * wp + lg * 4;
      *(uint2*)&sUT[l16 * 128 + (((l0r >> 3) ^ xs) << 4) + (l0r & 7) * 2] =
          make_uint2(pkbf(ua[0], ua[1]), pkbf(ua[2], ua[3]));
    }
    WAITLGKM; BARRIER();  // B2: sUT ready

    // ---- ph3: Wacc += KpT(p-strip) * U ----
    const bf16x8 bu0 = *(const bf16x8*)&sUT[l16 * 128 + ((lg ^ xs) << 4)];
    const bf16x8 bu1 = *(const bf16x8*)&sUT[l16 * 128 + (((4 + lg) ^ xs) << 4)];
#pragma unroll
    for (int mt = 0; mt < 4; mt++) {
      const int pr = mt * 16 + l16;
      const bf16x8 ka0 = *(const bf16x8*)&RB[pr * 128 + ((lg ^ xs) << 4)];
      Wacc[mt] = MFMA(ka0, bu0, Wacc[mt]);
      const bf16x8 ka1 = *(const bf16x8*)&RB[pr * 128 + (((4 + lg) ^ xs) << 4)];
      Wacc[mt] = MFMA(ka1, bu1, Wacc[mt]);
    }
    WAITLGKM;   // RB reads drained before overwrite
    if (c < NCHK - 1) {
#pragma unroll
      for (int j = 0; j < 8; j++)
        gl_lds16(KpTN + (size_t)w * 8192 + j * 1024 + lane * 16, RB + j * 1024);
      MEMFENCE;
    }
    // sWT <- bf16(W_new); readers are next chunk's ph1 (after B4)
#pragma unroll
    for (int mt = 0; mt < 4; mt++) {
      const int p0m = w * 64 + mt * 16 + lg * 4;
      *(uint2*)&sWT[l16 * 1024 + (((p0m >> 3) ^ xs) << 4) + (p0m & 7) * 2] =
          make_uint2(pkbf(Wacc[mt][0], Wacc[mt][1]), pkbf(Wacc[mt][2], Wacc[mt][3]));
    }

    // ---- ph4: partial out = Qp(half h) * W_old (wb regs) ----
    if (c < NCHK - 1) { WAITV(8); } else { WAITV(0); }   // Qp ready
    f32x4 o0 = (f32x4){0.f,0.f,0.f,0.f}, o1 = (f32x4){0.f,0.f,0.f,0.f};
#pragma unroll
    for (int ks = 0; ks < 8; ks += 2) {
      const bf16x8 qa0 = *(const bf16x8*)&RA[l16 * 512 + (((ks * 4 + lg) ^ xs) << 4)];
      o0 = MFMA(qa0, wb[ks], o0);
      const bf16x8 qa1 = *(const bf16x8*)&RA[l16 * 512 + ((((ks + 1) * 4 + lg) ^ xs) << 4)];
      o1 = MFMA(qa1, wb[ks + 1], o1);
    }
    WAITLGKM;   // RA reads drained before overwrite
    if (c < NCHK - 1) {
#pragma unroll
      for (int j = 0; j < 8; j++)
        gl_lds16(KpN + (size_t)(16 * wp + 2 * j + (lane >> 5)) * 1024 + h * 512 + (lane & 31) * 16,
                 RA + j * 1024);
      MEMFENCE;
    }
    if (h) {
      float4 pv;
      pv.x = o0[0] + o1[0]; pv.y = o0[1] + o1[1];
      pv.z = o0[2] + o1[2]; pv.w = o0[3] + o1[3];
      *(float4*)&pbuf[wp][l16][lg * 4] = pv;
    } else {
      o0 = MFMA(gf0, bu0, o0);   // + Gl * U (tril-inclusive, positive)
      o1 = MFMA(gf1, bu1, o1);
    }
    WAITLGKM; BARRIER();  // B4: out partials + sWT(new) ready

    if (!h) {
      const float4 po = *(const float4*)&pbuf[wp][l16][lg * 4];
      const float pr4[4] = {po.x, po.y, po.z, po.w};
      const int colb = hd * 64 + dq * 16 + l16;
#pragma unroll
      for (int reg = 0; reg < 4; reg++) {
        const int l = c * 64 + 16 * wp + lg * 4 + reg;
        const int r = l * BSZN + bidx;
        const int cp = (colb & ~63) | ((((colb >> 3) & 7) ^ (r & 7)) << 3) | (colb & 7);
        lobf[(size_t)r * DMODEL + cp] = f2b(0.125f * (o0[reg] + o1[reg] + pr4[reg]));
      }
    }
  }
}

// ---------------------------------------------------------------------------
// K5b: LayerNorm (unchanged)
// ---------------------------------------------------------------------------
__global__ __launch_bounds__(256)
void k_ln(const float* __restrict__ ao, const float* __restrict__ gamma,
          const float* __restrict__ beta, float* __restrict__ out)
{
  const int row = blockIdx.x;
  const int tid = threadIdx.x;
  __shared__ float r1[4], r2[4];
  const float4 v = *(const float4*)&ao[(size_t)row * DMODEL + tid * 4];
  float s1 = v.x + v.y + v.z + v.w;
  float s2 = v.x * v.x + v.y * v.y + v.z * v.z + v.w * v.w;
  for (int off = 32; off > 0; off >>= 1) {
    s1 += __shfl_down(s1, off);
    s2 += __shfl_down(s2, off);
  }
  if ((tid & 63) == 0) { r1[tid >> 6] = s1; r2[tid >> 6] = s2; }
  __syncthreads();
  const float ts1 = r1[0] + r1[1] + r1[2] + r1[3];
  const float ts2 = r2[0] + r2[1] + r2[2] + r2[3];
  const float mu = ts1 * (1.f / DMODEL);
  const float var = ts2 * (1.f / DMODEL) - mu * mu;
  const float rs = rsqrtf(var + 1e-5f);
  const float4 g = *(const float4*)&gamma[tid * 4];
  const float4 b = *(const float4*)&beta[tid * 4];
  float4 o;
  o.x = (v.x - mu) * rs * g.x + b.x;
  o.y = (v.y - mu) * rs * g.y + b.y;
  o.z = (v.z - mu) * rs * g.z + b.z;
  o.w = (v.w - mu) * rs * g.w + b.w;
  *(float4*)&out[(size_t)row * DMODEL + tid * 4] = o;
}

// ---------------------------------------------------------------------------
extern "C" void kernel_launch(void* const* d_in, const int* in_sizes, int n_in,
                              void* d_out, int out_size, void* d_ws, size_t ws_size,
                              hipStream_t stream)
{
  (void)in_sizes; (void)n_in; (void)out_size; (void)ws_size;
  const float* h   = (const float*)d_in[0];
  const float* Wq  = (const float*)d_in[1];
  const float* Wo  = (const float*)d_in[2];
  const float* gam = (const float*)d_in[3];
  const float* bet = (const float*)d_in[4];
  const float* pm  = (const float*)d_in[5];
  float* out = (float*)d_out;

  char* ws = (char*)d_ws;
  size_t off = 0;
  auto alloc = [&](size_t bytes) -> void* {
    void* p = ws + off;
    off += (bytes + 255) & ~(size_t)255;
    return p;
  };
  // total workspace ~= 229 MB
  bf16*  vh  = (bf16*)alloc((size_t)BHN * LSEQ * DH * 2);            //  8.4 MB
  float* bbf = (float*)alloc((size_t)BHN * LSEQ * 4);                //  0.3 MB
  bf16*  Kp  = (bf16*)alloc((size_t)BHN * LSEQ * PF * 2);            // 67.1 MB
  bf16*  Qp  = (bf16*)alloc((size_t)BHN * LSEQ * PF * 2);            // 67.1 MB
  bf16*  Tm  = (bf16*)alloc((size_t)BHN * NCHK * CHK * CHK * 2);     //  8.4 MB
  bf16*  Gll = (bf16*)alloc((size_t)BHN * NCHK * CHK * CHK * 2);     //  8.4 MB
  char*  R   = (char*)alloc((size_t)BHN * NCHK * 512 * 64 * 2);      // 67.1 MB shared
  bf16*  WoT = (bf16*)alloc((size_t)DMODEL * DMODEL * 2);            //  2.1 MB
  bf16*  pmThi = (bf16*)alloc((size_t)MPROJ * 64 * 2);               // 32 KB
  bf16*  pmTlo = (bf16*)alloc((size_t)MPROJ * 64 * 2);               // 32 KB
  // region R lifetimes:
  //  phase1 (prep/qkvb/featm): qh(8.4) | kh(8.4) | hbf(8.4) | WqT(6.6)
  //  phase2 (sgsolve/scan):    KpT (67.1)
  //  phase3 (outgemm/ln):      ao (16.8 f32)
  bf16*  qh  = (bf16*)R;
  bf16*  kh  = (bf16*)(R + (size_t)BHN * LSEQ * DH * 2);
  bf16*  hbf = (bf16*)(R + (size_t)2 * BHN * LSEQ * DH * 2);
  bf16*  WqT = (bf16*)(R + (size_t)3 * BHN * LSEQ * DH * 2);
  bf16*  KpT = (bf16*)R;
  float* ao  = (float*)R;
  bf16*  lobf = (bf16*)d_out;   // d_out scratch; fully rewritten by k_ln

  k_prep     <<<dim3(3105),                       256, 0, stream>>>(h, hbf, Wq, WqT, Wo, WoT, pm, pmThi, pmTlo);
  k_gemm_qkvb<<<dim3(NQPAD / 128, 4096 / 128),    256, 0, stream>>>(hbf, WqT, qh, kh, vh, bbf);
  k_featm    <<<dim3(LSEQ / 64, BHN),             256, 0, stream>>>(qh, kh, pmThi, pmTlo, Qp, Kp);
  k_sgsolve  <<<dim3(NCHK, BHN),                  256, 0, stream>>>(Kp, Qp, bbf, Gll, Tm, KpT);
  k_scan     <<<dim3(128),                        512, 0, stream>>>(Kp, Qp, vh, Tm, Gll, KpT, lobf);
  k_gemm_out <<<dim3(DMODEL / 128, 4096 / 128),   256, 0, stream>>>(lobf, WoT, h, ao);
  k_ln       <<<dim3(4096),                       256, 0, stream>>>(ao, gam, bet, out);
}